// Round 3
// baseline (449.206 us; speedup 1.0000x reference)
//
#include <hip/hip_runtime.h>
#include <cstdint>

typedef unsigned short ushort_t;
typedef __bf16 bf16x8 __attribute__((ext_vector_type(8)));
typedef float f32x4 __attribute__((ext_vector_type(4)));

__device__ __forceinline__ ushort_t f2b(float f) {
  union { float f; unsigned u; } v; v.f = f;
  unsigned u = v.u;
  return (ushort_t)((u + 0x7FFFu + ((u >> 16) & 1u)) >> 16);
}
__device__ __forceinline__ float b2f(ushort_t h) {
  union { unsigned u; float f; } v; v.u = ((unsigned)h) << 16;
  return v.f;
}

// fast sigmoid-gelu: v * rcp(1 + exp(-1.702 v)); error suppressed by gamma=1e-6
__device__ __forceinline__ float fgelu(float v) {
  float e = __expf(v * -1.702f);
  return v * __builtin_amdgcn_rcpf(1.0f + e);
}

// f32 -> bf16 cast for weights
__global__ __launch_bounds__(256) void k_tobf16(const float* __restrict__ s,
                                                ushort_t* __restrict__ d, int n) {
  int i = blockIdx.x * 256 + threadIdx.x;
  if (i < n) d[i] = f2b(s[i]);
}

// p[b,c] = mean over 32x32 spatial; one wave per (b,c)
__global__ __launch_bounds__(256) void k_pool(const float* __restrict__ x,
                                              float* __restrict__ p) {
  int wid = threadIdx.x >> 6, lane = threadIdx.x & 63;
  int bc = blockIdx.x * 4 + wid;
  const float4* xr = (const float4*)(x + (size_t)bc * 1024);
  float s = 0.f;
#pragma unroll
  for (int i = 0; i < 4; ++i) {
    float4 t = xr[i * 64 + lane];
    s += (t.x + t.y) + (t.z + t.w);
  }
#pragma unroll
  for (int off = 32; off > 0; off >>= 1) s += __shfl_down(s, off);
  if (lane == 0) p[bc] = s * (1.0f / 1024.0f);
}

// h[b][o] = relu(bn(p[b] . kp_w1[o])); one wave per (o,b); grid (24,64), block 64
__global__ __launch_bounds__(64) void k_h(
    const float* __restrict__ p, const float* __restrict__ kp_w1,
    const float* __restrict__ bn_gamma, const float* __restrict__ bn_beta,
    const float* __restrict__ bn_mean, const float* __restrict__ bn_var,
    float* __restrict__ hbuf) {
  int o = blockIdx.x, b = blockIdx.y, lane = threadIdx.x;
  const float* pr = p + b * 384;
  const float* wr = kp_w1 + o * 384;
  float s = 0.f;
#pragma unroll
  for (int i = 0; i < 6; ++i) {
    int c = i * 64 + lane;
    s += pr[c] * wr[c];
  }
#pragma unroll
  for (int off = 32; off > 0; off >>= 1) s += __shfl_down(s, off);
  if (lane == 0) {
    float a = (s - bn_mean[o]) * rsqrtf(bn_var[o] + 1e-5f) * bn_gamma[o] + bn_beta[o];
    hbuf[b * 24 + o] = fmaxf(a, 0.f);
  }
}

// praw[b][j] = h[b].kp_w2[j] + kp_b2[j]; per-block partial sums -> part[b][bx]
// grid (96, 64), block 256
__global__ __launch_bounds__(256) void k_praw(
    const float* __restrict__ hbuf, const float* __restrict__ kp_w2,
    const float* __restrict__ kp_b2, float* __restrict__ praw,
    float2* __restrict__ part) {
  __shared__ float wrow[256 * 25];
  __shared__ float hs[24];
  __shared__ float r1[256], r2[256];
  int bx = blockIdx.x, b = blockIdx.y, tid = threadIdx.x;
  int j0 = bx * 256;
  for (int t = tid; t < 6144; t += 256) {
    int row = t / 24, col = t - row * 24;
    wrow[row * 25 + col] = kp_w2[(size_t)j0 * 24 + t];
  }
  if (tid < 24) hs[tid] = hbuf[b * 24 + tid];
  __syncthreads();
  float a = kp_b2[j0 + tid];
  const float* wr = wrow + tid * 25;
#pragma unroll
  for (int r = 0; r < 24; ++r) a += hs[r] * wr[r];
  praw[(size_t)b * 24576 + j0 + tid] = a;
  r1[tid] = a; r2[tid] = a * a;
  __syncthreads();
  for (int off = 128; off > 0; off >>= 1) {
    if (tid < off) { r1[tid] += r1[tid + off]; r2[tid] += r2[tid + off]; }
    __syncthreads();
  }
  if (tid == 0) part[b * 96 + bx] = make_float2(r1[0], r2[0]);
}

// stats[b] = (u, rsqrt(var)); grid 64, block 128 (96 active)
__global__ __launch_bounds__(128) void k_pstat(const float2* __restrict__ part,
                                               float2* __restrict__ stats) {
  __shared__ float r1[128], r2[128];
  int b = blockIdx.x, tid = threadIdx.x;
  float2 v = (tid < 96) ? part[b * 96 + tid] : make_float2(0.f, 0.f);
  r1[tid] = v.x; r2[tid] = v.y;
  __syncthreads();
  for (int off = 64; off > 0; off >>= 1) {
    if (tid < off) { r1[tid] += r1[tid + off]; r2[tid] += r2[tid + off]; }
    __syncthreads();
  }
  if (tid == 0) {
    float u = r1[0] * (1.f / 24576.f);
    float var = r2[0] * (1.f / 24576.f) - u * u;
    stats[b] = make_float2(u, rsqrtf(var + 1e-12f));
  }
}

// circulant conv per (b,c); writes y NCHW bf16 = conv + bias.
// Frame-norm affine applied on param load. grid (384, 64)
__global__ __launch_bounds__(256) void k_conv(const float* __restrict__ x,
                                              const float* __restrict__ praw,
                                              const float2* __restrict__ stats,
                                              const float* __restrict__ fn_std,
                                              const float* __restrict__ fn_mean,
                                              const float* __restrict__ bias,
                                              ushort_t* __restrict__ y) {
  __shared__ float xs[1024];
  __shared__ float pe[32];
  __shared__ float kn[32];
  int c = blockIdx.x, b = blockIdx.y;
  int tid = threadIdx.x;
  size_t plane = ((size_t)b * 384 + c) * 1024;
  float4 xv = ((const float4*)(x + plane))[tid];
  if (tid < 32) {
    float2 st = stats[b];
    int j1 = c * 32 + tid;
    int j2 = (384 + c) * 32 + tid;
    pe[tid] = (praw[(size_t)b * 24576 + j1] - st.x) * st.y * fn_std[j1] + fn_mean[j1];
    kn[tid] = (praw[(size_t)b * 24576 + j2] - st.x) * st.y * fn_std[j2] + fn_mean[j2];
  }
  __syncthreads();
  const bool hm = (c < 192);
  {
    int e0 = tid * 4;
    float4 t;
    if (hm) {
      float pv = pe[e0 >> 5];
      t.x = xv.x + pv; t.y = xv.y + pv; t.z = xv.z + pv; t.w = xv.w + pv;
    } else {
      int w0 = e0 & 31;
      t.x = xv.x + pe[w0]; t.y = xv.y + pe[w0 + 1];
      t.z = xv.z + pe[w0 + 2]; t.w = xv.w + pe[w0 + 3];
    }
    *(float4*)(xs + e0) = t;
  }
  __syncthreads();
  int ww = tid & 31, hh0 = (tid >> 5) * 4;
  float a0 = 0, a1 = 0, a2 = 0, a3 = 0;
  if (hm) {
    float c0 = xs[hh0 * 32 + ww], c1 = xs[(hh0 + 1) * 32 + ww];
    float c2 = xs[(hh0 + 2) * 32 + ww], c3 = xs[(hh0 + 3) * 32 + ww];
#pragma unroll
    for (int d = 0; d < 32; ++d) {
      float kv = kn[d];
      a0 += kv * c0; a1 += kv * c1; a2 += kv * c2; a3 += kv * c3;
      c0 = c1; c1 = c2; c2 = c3;
      c3 = xs[(((hh0 + d + 4) & 31) << 5) + ww];
    }
  } else {
#pragma unroll
    for (int d = 0; d < 32; ++d) {
      float kv = kn[d];
      int wc = (ww + d) & 31;
      a0 += kv * xs[(hh0    ) * 32 + wc];
      a1 += kv * xs[(hh0 + 1) * 32 + wc];
      a2 += kv * xs[(hh0 + 2) * 32 + wc];
      a3 += kv * xs[(hh0 + 3) * 32 + wc];
    }
  }
  float bv = bias[c];
  ushort_t* yo = y + plane;
  yo[(hh0    ) * 32 + ww] = f2b(a0 + bv);
  yo[(hh0 + 1) * 32 + ww] = f2b(a1 + bv);
  yo[(hh0 + 2) * 32 + ww] = f2b(a2 + bv);
  yo[(hh0 + 3) * 32 + ww] = f2b(a3 + bv);
}

// LayerNorm over C=384 + NCHW->NHWC transpose. Block per (b,h); out NHWC bf16.
__global__ __launch_bounds__(256) void k_lnT(const ushort_t* __restrict__ y,
                                             const float* __restrict__ lw,
                                             const float* __restrict__ lb,
                                             ushort_t* __restrict__ t) {
  __shared__ ushort_t tl[32 * 392];
  __shared__ float rsum[8][32], rsq[8][32];
  __shared__ float smu[32], srs[32];
  int bh = blockIdx.x;
  int b = bh >> 5, h = bh & 31;
  int tid = threadIdx.x;
  int w = tid & 31, cg = tid >> 5;
  const ushort_t* base = y + ((size_t)b * 384) * 1024 + h * 32 + w;
  float v[48];
  float s1 = 0.f, s2 = 0.f;
#pragma unroll
  for (int k = 0; k < 48; ++k) {
    int c = cg * 48 + k;
    float f = b2f(base[(size_t)c * 1024]);
    v[k] = f; s1 += f; s2 += f * f;
  }
  rsum[cg][w] = s1; rsq[cg][w] = s2;
  __syncthreads();
  if (tid < 32) {
    float a = 0.f, q = 0.f;
#pragma unroll
    for (int g = 0; g < 8; ++g) { a += rsum[g][tid]; q += rsq[g][tid]; }
    float mu = a * (1.f / 384.f);
    float var = q * (1.f / 384.f) - mu * mu;
    smu[tid] = mu; srs[tid] = rsqrtf(var + 1e-6f);
  }
  __syncthreads();
  float mu = smu[w], rs = srs[w];
#pragma unroll
  for (int k = 0; k < 48; ++k) {
    int c = cg * 48 + k;
    tl[w * 392 + c] = f2b((v[k] - mu) * rs * lw[c] + lb[c]);
  }
  __syncthreads();
  ushort_t* orow = t + (size_t)bh * 32 * 384;
#pragma unroll
  for (int i = 0; i < 6; ++i) {
    int flat16 = i * 256 + tid;
    int ww = flat16 / 48, c8 = flat16 % 48;
    *(uint4*)(orow + ww * 384 + c8 * 8) = *(const uint4*)(tl + ww * 392 + c8 * 8);
  }
}

__device__ __forceinline__ void gl_lds16(const void* g, void* l) {
  __builtin_amdgcn_global_load_lds(
      (const __attribute__((address_space(1))) unsigned int*)g,
      (__attribute__((address_space(3))) unsigned int*)l, 16, 0, 0);
}

// ---------------- GEMM1 (barrier-free K-loop) ----------------
// hid[m,n] = gelu(A[M,384] @ Bt[1536,384]^T + bias)
// Block: 512 thr (8 waves), tile 256m x 128n. Full-K B panel (128x384 bf16,
// 96KB) staged to LDS ONCE (XOR-swizzled), A streamed global->reg with
// depth-2 prefetch. After one barrier the K-loop has NO barriers/fences.
template <int T>
__device__ __forceinline__ void g1_step(const ushort_t* Bs, const ushort_t* Ab,
                                        int wn, int l16, int quad,
                                        bf16x8 (&afc)[4], bf16x8 (&afl)[4],
                                        f32x4 (&acc)[4][4]) {
  const int K = 384;
  if (T + 2 < 12) {
#pragma unroll
    for (int i = 0; i < 4; ++i)
      afl[i] = *(const bf16x8*)(Ab + (size_t)i * 16 * K + (T + 2) * 32);
  }
  bf16x8 bfr[4];
  const int pos = (T * 4 + quad) ^ (l16 & 7);
#pragma unroll
  for (int j = 0; j < 4; ++j) {
    int r = wn + j * 16 + l16;
    bfr[j] = *(const bf16x8*)(Bs + r * 384 + pos * 8);
  }
#pragma unroll
  for (int i = 0; i < 4; ++i)
#pragma unroll
    for (int j = 0; j < 4; ++j)  // swapped operands -> transposed D
      acc[i][j] = __builtin_amdgcn_mfma_f32_16x16x32_bf16(bfr[j], afc[i],
                                                          acc[i][j], 0, 0, 0);
}

__global__ __launch_bounds__(512) void k_gemm1(const ushort_t* __restrict__ A,
                                               const ushort_t* __restrict__ Bt,
                                               const float* __restrict__ bias,
                                               ushort_t* __restrict__ out) {
  const int N = 1536;
  const int K = 384;
  __shared__ ushort_t Bs[128 * 384];  // 96KB full-K B panel (swizzled)
  const int tid = threadIdx.x;
  const int wid = tid >> 6;
  const int lane = tid & 63;
  const int quad = lane >> 4;
  const int l16 = lane & 15;
  int lin = blockIdx.y * 12 + blockIdx.x;
  const int cpx = (12 * (int)gridDim.y) >> 3;  // nwg/8, nwg%8==0
  lin = (lin & 7) * cpx + (lin >> 3);          // XCD-chunked: n fastest in-chunk
  const int mb = lin / 12;
  const int nb = lin - mb * 12;
  const int m0 = mb * 256 + (wid & 3) * 64;    // wave m base
  const int wn = (wid >> 2) * 64;              // wave n within B panel
  // ---- stage full B panel once; swizzle: LDS[r][c] = G[r][c ^ (r&7)] ----
#pragma unroll
  for (int it = 0; it < 12; ++it) {
    int s = it * 512 + tid;
    int r = s / 48;
    int c = s - r * 48;
    int g = c ^ (r & 7);
    gl_lds16(Bt + (size_t)(nb * 128 + r) * K + g * 8,
             Bs + (size_t)(it * 512 + wid * 64) * 8);
  }
  __builtin_amdgcn_sched_barrier(0);
  // ---- A depth-2 register prefetch (t=0,1) ----
  const ushort_t* Ab = A + (size_t)(m0 + l16) * K + quad * 8;
  bf16x8 af0[4], af1[4], af2[4];
#pragma unroll
  for (int i = 0; i < 4; ++i) af0[i] = *(const bf16x8*)(Ab + (size_t)i * 16 * K);
#pragma unroll
  for (int i = 0; i < 4; ++i) af1[i] = *(const bf16x8*)(Ab + (size_t)i * 16 * K + 32);
  asm volatile("s_waitcnt vmcnt(8)" ::: "memory");  // B-stage (12 oldest) done
  __builtin_amdgcn_s_barrier();
  // ---- barrier-free K loop (12 steps, rotating af sets) ----
  f32x4 acc[4][4] = {};
  g1_step<0>(Bs, Ab, wn, l16, quad, af0, af2, acc);
  g1_step<1>(Bs, Ab, wn, l16, quad, af1, af0, acc);
  g1_step<2>(Bs, Ab, wn, l16, quad, af2, af1, acc);
  g1_step<3>(Bs, Ab, wn, l16, quad, af0, af2, acc);
  g1_step<4>(Bs, Ab, wn, l16, quad, af1, af0, acc);
  g1_step<5>(Bs, Ab, wn, l16, quad, af2, af1, acc);
  g1_step<6>(Bs, Ab, wn, l16, quad, af0, af2, acc);
  g1_step<7>(Bs, Ab, wn, l16, quad, af1, af0, acc);
  g1_step<8>(Bs, Ab, wn, l16, quad, af2, af1, acc);
  g1_step<9>(Bs, Ab, wn, l16, quad, af0, af2, acc);
  g1_step<10>(Bs, Ab, wn, l16, quad, af1, af0, acc);
  g1_step<11>(Bs, Ab, wn, l16, quad, af2, af1, acc);
  // ---- epilogue: lane holds m = m0+l16 (+i*16), n = nb*128+wn+j*16+quad*4+r
  const size_t mrow = (size_t)(m0 + l16) * N;
#pragma unroll
  for (int j = 0; j < 4; ++j) {
    const int nbg = nb * 128 + wn + j * 16 + quad * 4;
    const float4 bv = *(const float4*)(bias + nbg);
#pragma unroll
    for (int i = 0; i < 4; ++i) {
      float v0 = fgelu(acc[i][j][0] + bv.x);
      float v1 = fgelu(acc[i][j][1] + bv.y);
      float v2 = fgelu(acc[i][j][2] + bv.z);
      float v3 = fgelu(acc[i][j][3] + bv.w);
      unsigned lo, hi;
      asm("v_cvt_pk_bf16_f32 %0, %1, %2" : "=v"(lo) : "v"(v0), "v"(v1));
      asm("v_cvt_pk_bf16_f32 %0, %1, %2" : "=v"(hi) : "v"(v2), "v"(v3));
      *(uint2*)(out + mrow + (size_t)(i * 16) * N + nbg) = make_uint2(lo, hi);
    }
  }
}

// GEMM2 + fused residual: out[b,c,sp] = x + (A@Bt^T + b2)*gamma, NCHW via LDS
// 3-buffer counted-vmcnt pipeline; epilogue transpose buffer aliased
__global__ __launch_bounds__(256) void k_gemm2(const ushort_t* __restrict__ A,
                                               const ushort_t* __restrict__ Bt,
                                               const float* __restrict__ bias,
                                               const float* __restrict__ scale,
                                               const float* __restrict__ x,
                                               float* __restrict__ out,
                                               int mbase) {
  const int K = 1536;
  const int nt = 48;
  __shared__ __align__(16) char smem[49152];
  ushort_t* AsB = (ushort_t*)smem;        // 3 x 4096 ushorts
  ushort_t* BsB = AsB + 12288;            // 3 x 4096 ushorts
  float* tb = (float*)smem;               // epilogue transpose (aliased, 33792B)
  const int tid = threadIdx.x;
  const int wid = tid >> 6;
  const int lane = tid & 63;
  const int quad = lane >> 4;
  const int l16 = lane & 15;
  int lin = blockIdx.y * 3 + blockIdx.x;
  const int cpx = (3 * (int)gridDim.y) >> 3;
  lin = (lin & 7) * cpx + (lin >> 3);
  const int m0 = (lin / 3) * 128;
  const int n0 = (lin % 3) * 128;
  const int wm = (wid & 1) * 64;
  const int wn = (wid >> 1) * 64;
  const int row = tid >> 2;
  const int seg = (tid & 3) ^ ((tid >> 3) & 3);
  const int quadA = quad ^ ((l16 >> 1) & 3);
  const ushort_t* Ag0 = A + (size_t)(m0 + row) * K + seg * 8;
  const ushort_t* Ag1 = Ag0 + (size_t)64 * K;
  const ushort_t* Bg0 = Bt + (size_t)(n0 + row) * K + seg * 8;
  const ushort_t* Bg1 = Bg0 + (size_t)64 * K;
  const int wo = wid * 512;
  f32x4 acc[4][4] = {};
  // prologue
  gl_lds16(Ag0, AsB + wo);
  gl_lds16(Ag1, AsB + wo + 2048);
  gl_lds16(Bg0, BsB + wo);
  gl_lds16(Bg1, BsB + wo + 2048);
  gl_lds16(Ag0 + 32, AsB + 4096 + wo);
  gl_lds16(Ag1 + 32, AsB + 4096 + wo + 2048);
  gl_lds16(Bg0 + 32, BsB + 4096 + wo);
  gl_lds16(Bg1 + 32, BsB + 4096 + wo + 2048);
  int rb = 0, wb = 2;
  for (int t = 0; t < nt - 1; ++t) {
    asm volatile("s_waitcnt vmcnt(4)" ::: "memory");
    __builtin_amdgcn_s_barrier();
    __builtin_amdgcn_sched_barrier(0);
    if (t < nt - 2) {
      const int k2 = (t + 2) << 5;
      ushort_t* Asn = AsB + wb * 4096;
      ushort_t* Bsn = BsB + wb * 4096;
      gl_lds16(Ag0 + k2, Asn + wo);
      gl_lds16(Ag1 + k2, Asn + wo + 2048);
      gl_lds16(Bg0 + k2, Bsn + wo);
      gl_lds16(Bg1 + k2, Bsn + wo + 2048);
    }
    const ushort_t* Asc = AsB + rb * 4096;
    const ushort_t* Bsc = BsB + rb * 4096;
    bf16x8 af[4], bfr[4];
#pragma unroll
    for (int i = 0; i < 4; ++i)
      af[i] = *(const bf16x8*)(Asc + (wm + i * 16 + l16) * 32 + quadA * 8);
#pragma unroll
    for (int j = 0; j < 4; ++j)
      bfr[j] = *(const bf16x8*)(Bsc + (wn + j * 16 + l16) * 32 + quadA * 8);
#pragma unroll
    for (int i = 0; i < 4; ++i)
#pragma unroll
      for (int j = 0; j < 4; ++j)
        acc[i][j] = __builtin_amdgcn_mfma_f32_16x16x32_bf16(af[i], bfr[j], acc[i][j], 0, 0, 0);
    rb = (rb == 2) ? 0 : rb + 1;
    wb = (wb == 2) ? 0 : wb + 1;
  }
  // final tile
  asm volatile("s_waitcnt vmcnt(0)" ::: "memory");
  __builtin_amdgcn_s_barrier();
  __builtin_amdgcn_sched_barrier(0);
  {
    const ushort_t* Asc = AsB + rb * 4096;
    const ushort_t* Bsc = BsB + rb * 4096;
    bf16x8 af[4], bfr[4];
#pragma unroll
    for (int i = 0; i < 4; ++i)
      af[i] = *(const bf16x8*)(Asc + (wm + i * 16 + l16) * 32 + quadA * 8);
#pragma unroll
    for (int j = 0; j < 4; ++j)
      bfr[j] = *(const bf16x8*)(Bsc + (wn + j * 16 + l16) * 32 + quadA * 8);
#pragma unroll
    for (int i = 0; i < 4; ++i)
#pragma unroll
      for (int j = 0; j < 4; ++j)
        acc[i][j] = __builtin_amdgcn_mfma_f32_16x16x32_bf16(af[i], bfr[j], acc[i][j], 0, 0, 0);
  }
  const int mg = mbase + m0;
  const int b = mg >> 10;
  const int sp0 = mg & 1023;
#pragma unroll
  for (int p = 0; p < 2; ++p) {
    __syncthreads();
    if ((wid >> 1) == p) {
#pragma unroll
      for (int j = 0; j < 4; ++j) {
        int nl = j * 16 + l16;
        int cch = n0 + p * 64 + nl;
        float bv = bias[cch], sv = scale[cch];
#pragma unroll
        for (int i = 0; i < 4; ++i) {
          int ml = wm + i * 16 + quad * 4;
          *(float4*)(tb + nl * 132 + ml) = make_float4(
              (acc[i][j][0] + bv) * sv, (acc[i][j][1] + bv) * sv,
              (acc[i][j][2] + bv) * sv, (acc[i][j][3] + bv) * sv);
        }
      }
    }
    __syncthreads();
#pragma unroll
    for (int q = 0; q < 8; ++q) {
      int flat4 = q * 256 + tid;
      int cl = flat4 >> 5;
      int m4 = (flat4 & 31) << 2;
      size_t ga = (((size_t)b * 384 + n0 + p * 64 + cl) << 10) + sp0 + m4;
      float4 xv = *(const float4*)(x + ga);
      float4 tv = *(const float4*)(tb + cl * 132 + m4);
      *(float4*)(out + ga) = make_float4(xv.x + tv.x, xv.y + tv.y,
                                         xv.z + tv.z, xv.w + tv.w);
    }
  }
}

extern "C" void kernel_launch(void* const* d_in, const int* in_sizes, int n_in,
                              void* d_out, int out_size, void* d_ws, size_t ws_size,
                              hipStream_t stream) {
  const float* x        = (const float*)d_in[0];
  const float* kp_w1    = (const float*)d_in[1];
  const float* bn_gamma = (const float*)d_in[2];
  const float* bn_beta  = (const float*)d_in[3];
  const float* bn_mean  = (const float*)d_in[4];
  const float* bn_var   = (const float*)d_in[5];
  const float* kp_w2    = (const float*)d_in[6];
  const float* kp_b2    = (const float*)d_in[7];
  const float* fn_std   = (const float*)d_in[8];
  const float* fn_mean  = (const float*)d_in[9];
  const float* bias     = (const float*)d_in[10];
  const float* ln_w     = (const float*)d_in[11];
  const float* ln_b     = (const float*)d_in[12];
  const float* w1       = (const float*)d_in[13];
  const float* b1       = (const float*)d_in[14];
  const float* w2       = (const float*)d_in[15];
  const float* b2       = (const float*)d_in[16];
  const float* gamma    = (const float*)d_in[17];
  float* out = (float*)d_out;

  char* ws = (char*)d_ws;
  float*    praw   = (float*)(ws + 0);            // 6291456
  float*    pB     = (float*)(ws + 6291456);      // 98304
  float*    hbuf   = (float*)(ws + 6389760);      // 6144
  float2*   part   = (float2*)(ws + 6395904);     // 49152
  float2*   stats  = (float2*)(ws + 6445056);     // 512
  ushort_t* w1b    = (ushort_t*)(ws + 6445568);   // 1179648
  ushort_t* w2b    = (ushort_t*)(ws + 7625216);   // 1179648
  ushort_t* ybuf   = (ushort_t*)(ws + 8804864);   // 50331648
  ushort_t* tn     = (ushort_t*)(ws + 59136512);  // 50331648
  ushort_t* hid    = (ushort_t*)(ws + 109468160); // up to 201326592

  // chunking: hid for M-rows/chunk of the 65536-row MLP
  int nchunks;
  if (ws_size >= 310794752ULL) nchunks = 1;
  else if (ws_size >= 210131456ULL) nchunks = 2;
  else nchunks = 4;
  int mrows = 65536 / nchunks;

  k_tobf16<<<2304, 256, 0, stream>>>(w1, w1b, 589824);
  k_tobf16<<<2304, 256, 0, stream>>>(w2, w2b, 589824);
  k_pool<<<6144, 256, 0, stream>>>(x, pB);
  k_h<<<dim3(24, 64), 64, 0, stream>>>(pB, kp_w1, bn_gamma, bn_beta, bn_mean,
                                       bn_var, hbuf);
  k_praw<<<dim3(96, 64), 256, 0, stream>>>(hbuf, kp_w2, kp_b2, praw, part);
  k_pstat<<<64, 128, 0, stream>>>(part, stats);
  k_conv<<<dim3(384, 64), 256, 0, stream>>>(x, praw, stats, fn_std, fn_mean,
                                            bias, ybuf);
  k_lnT<<<2048, 256, 0, stream>>>(ybuf, ln_w, ln_b, tn);
  for (int s = 0; s < nchunks; ++s) {
    k_gemm1<<<dim3(12, mrows / 256), 512, 0, stream>>>(
        tn + (size_t)s * mrows * 384, w1b, b1, hid);
    k_gemm2<<<dim3(3, mrows / 128), 256, 0, stream>>>(
        hid, w2b, b2, gamma, x, out, s * mrows);
  }
}

// Round 4
// 413.390 us; speedup vs baseline: 1.0866x; 1.0866x over previous
//
#include <hip/hip_runtime.h>
#include <cstdint>

typedef unsigned short ushort_t;
typedef __bf16 bf16x8 __attribute__((ext_vector_type(8)));
typedef float f32x4 __attribute__((ext_vector_type(4)));

__device__ __forceinline__ ushort_t f2b(float f) {
  union { float f; unsigned u; } v; v.f = f;
  unsigned u = v.u;
  return (ushort_t)((u + 0x7FFFu + ((u >> 16) & 1u)) >> 16);
}
__device__ __forceinline__ float b2f(ushort_t h) {
  union { unsigned u; float f; } v; v.u = ((unsigned)h) << 16;
  return v.f;
}

// fast sigmoid-gelu: v * rcp(1 + exp(-1.702 v)); error suppressed by gamma=1e-6
__device__ __forceinline__ float fgelu(float v) {
  float e = __expf(v * -1.702f);
  return v * __builtin_amdgcn_rcpf(1.0f + e);
}

// f32 -> bf16 cast for weights
__global__ __launch_bounds__(256) void k_tobf16(const float* __restrict__ s,
                                                ushort_t* __restrict__ d, int n) {
  int i = blockIdx.x * 256 + threadIdx.x;
  if (i < n) d[i] = f2b(s[i]);
}

// pack w1 (1536x384 f32 row-major) into MFMA-fragment-major bf16:
// dst[((nb*12+kb)*64 + lane)*8 + e] = w1[(nb*16 + (lane&15))*384 + kb*32 + (lane>>4)*8 + e]
__global__ __launch_bounds__(256) void k_packw1(const float* __restrict__ w,
                                                ushort_t* __restrict__ d) {
  int flat = blockIdx.x * 256 + threadIdx.x;  // [0, 96*12*64)
  int lane = flat & 63;
  int frag = flat >> 6;
  int nb = frag / 12, kb = frag - nb * 12;
  const float* src = w + (size_t)(nb * 16 + (lane & 15)) * 384 + kb * 32 + (lane >> 4) * 8;
  ushort_t tmp[8];
#pragma unroll
  for (int e = 0; e < 8; ++e) tmp[e] = f2b(src[e]);
  *(uint4*)(d + (size_t)flat * 8) = *(const uint4*)tmp;
}

// p[b,c] = mean over 32x32 spatial; one wave per (b,c)
__global__ __launch_bounds__(256) void k_pool(const float* __restrict__ x,
                                              float* __restrict__ p) {
  int wid = threadIdx.x >> 6, lane = threadIdx.x & 63;
  int bc = blockIdx.x * 4 + wid;
  const float4* xr = (const float4*)(x + (size_t)bc * 1024);
  float s = 0.f;
#pragma unroll
  for (int i = 0; i < 4; ++i) {
    float4 t = xr[i * 64 + lane];
    s += (t.x + t.y) + (t.z + t.w);
  }
#pragma unroll
  for (int off = 32; off > 0; off >>= 1) s += __shfl_down(s, off);
  if (lane == 0) p[bc] = s * (1.0f / 1024.0f);
}

// h[b][o] = relu(bn(p[b] . kp_w1[o])); one wave per (o,b); grid (24,64), block 64
__global__ __launch_bounds__(64) void k_h(
    const float* __restrict__ p, const float* __restrict__ kp_w1,
    const float* __restrict__ bn_gamma, const float* __restrict__ bn_beta,
    const float* __restrict__ bn_mean, const float* __restrict__ bn_var,
    float* __restrict__ hbuf) {
  int o = blockIdx.x, b = blockIdx.y, lane = threadIdx.x;
  const float* pr = p + b * 384;
  const float* wr = kp_w1 + o * 384;
  float s = 0.f;
#pragma unroll
  for (int i = 0; i < 6; ++i) {
    int c = i * 64 + lane;
    s += pr[c] * wr[c];
  }
#pragma unroll
  for (int off = 32; off > 0; off >>= 1) s += __shfl_down(s, off);
  if (lane == 0) {
    float a = (s - bn_mean[o]) * rsqrtf(bn_var[o] + 1e-5f) * bn_gamma[o] + bn_beta[o];
    hbuf[b * 24 + o] = fmaxf(a, 0.f);
  }
}

// praw[b][j] = h[b].kp_w2[j] + kp_b2[j]; per-block partial sums -> part[b][bx]
// grid (96, 64), block 256
__global__ __launch_bounds__(256) void k_praw(
    const float* __restrict__ hbuf, const float* __restrict__ kp_w2,
    const float* __restrict__ kp_b2, float* __restrict__ praw,
    float2* __restrict__ part) {
  __shared__ float wrow[256 * 25];
  __shared__ float hs[24];
  __shared__ float r1[256], r2[256];
  int bx = blockIdx.x, b = blockIdx.y, tid = threadIdx.x;
  int j0 = bx * 256;
  for (int t = tid; t < 6144; t += 256) {
    int row = t / 24, col = t - row * 24;
    wrow[row * 25 + col] = kp_w2[(size_t)j0 * 24 + t];
  }
  if (tid < 24) hs[tid] = hbuf[b * 24 + tid];
  __syncthreads();
  float a = kp_b2[j0 + tid];
  const float* wr = wrow + tid * 25;
#pragma unroll
  for (int r = 0; r < 24; ++r) a += hs[r] * wr[r];
  praw[(size_t)b * 24576 + j0 + tid] = a;
  r1[tid] = a; r2[tid] = a * a;
  __syncthreads();
  for (int off = 128; off > 0; off >>= 1) {
    if (tid < off) { r1[tid] += r1[tid + off]; r2[tid] += r2[tid + off]; }
    __syncthreads();
  }
  if (tid == 0) part[b * 96 + bx] = make_float2(r1[0], r2[0]);
}

// stats[b] = (u, rsqrt(var)); grid 64, block 128 (96 active)
__global__ __launch_bounds__(128) void k_pstat(const float2* __restrict__ part,
                                               float2* __restrict__ stats) {
  __shared__ float r1[128], r2[128];
  int b = blockIdx.x, tid = threadIdx.x;
  float2 v = (tid < 96) ? part[b * 96 + tid] : make_float2(0.f, 0.f);
  r1[tid] = v.x; r2[tid] = v.y;
  __syncthreads();
  for (int off = 64; off > 0; off >>= 1) {
    if (tid < off) { r1[tid] += r1[tid + off]; r2[tid] += r2[tid + off]; }
    __syncthreads();
  }
  if (tid == 0) {
    float u = r1[0] * (1.f / 24576.f);
    float var = r2[0] * (1.f / 24576.f) - u * u;
    stats[b] = make_float2(u, rsqrtf(var + 1e-12f));
  }
}

// circulant conv per (b,c); writes y NCHW bf16 = conv + bias.
// Frame-norm affine applied on param load. grid (384, 64)
__global__ __launch_bounds__(256) void k_conv(const float* __restrict__ x,
                                              const float* __restrict__ praw,
                                              const float2* __restrict__ stats,
                                              const float* __restrict__ fn_std,
                                              const float* __restrict__ fn_mean,
                                              const float* __restrict__ bias,
                                              ushort_t* __restrict__ y) {
  __shared__ float xs[1024];
  __shared__ float pe[32];
  __shared__ float kn[32];
  int c = blockIdx.x, b = blockIdx.y;
  int tid = threadIdx.x;
  size_t plane = ((size_t)b * 384 + c) * 1024;
  float4 xv = ((const float4*)(x + plane))[tid];
  if (tid < 32) {
    float2 st = stats[b];
    int j1 = c * 32 + tid;
    int j2 = (384 + c) * 32 + tid;
    pe[tid] = (praw[(size_t)b * 24576 + j1] - st.x) * st.y * fn_std[j1] + fn_mean[j1];
    kn[tid] = (praw[(size_t)b * 24576 + j2] - st.x) * st.y * fn_std[j2] + fn_mean[j2];
  }
  __syncthreads();
  const bool hm = (c < 192);
  {
    int e0 = tid * 4;
    float4 t;
    if (hm) {
      float pv = pe[e0 >> 5];
      t.x = xv.x + pv; t.y = xv.y + pv; t.z = xv.z + pv; t.w = xv.w + pv;
    } else {
      int w0 = e0 & 31;
      t.x = xv.x + pe[w0]; t.y = xv.y + pe[w0 + 1];
      t.z = xv.z + pe[w0 + 2]; t.w = xv.w + pe[w0 + 3];
    }
    *(float4*)(xs + e0) = t;
  }
  __syncthreads();
  int ww = tid & 31, hh0 = (tid >> 5) * 4;
  float a0 = 0, a1 = 0, a2 = 0, a3 = 0;
  if (hm) {
    float c0 = xs[hh0 * 32 + ww], c1 = xs[(hh0 + 1) * 32 + ww];
    float c2 = xs[(hh0 + 2) * 32 + ww], c3 = xs[(hh0 + 3) * 32 + ww];
#pragma unroll
    for (int d = 0; d < 32; ++d) {
      float kv = kn[d];
      a0 += kv * c0; a1 += kv * c1; a2 += kv * c2; a3 += kv * c3;
      c0 = c1; c1 = c2; c2 = c3;
      c3 = xs[(((hh0 + d + 4) & 31) << 5) + ww];
    }
  } else {
#pragma unroll
    for (int d = 0; d < 32; ++d) {
      float kv = kn[d];
      int wc = (ww + d) & 31;
      a0 += kv * xs[(hh0    ) * 32 + wc];
      a1 += kv * xs[(hh0 + 1) * 32 + wc];
      a2 += kv * xs[(hh0 + 2) * 32 + wc];
      a3 += kv * xs[(hh0 + 3) * 32 + wc];
    }
  }
  float bv = bias[c];
  ushort_t* yo = y + plane;
  yo[(hh0    ) * 32 + ww] = f2b(a0 + bv);
  yo[(hh0 + 1) * 32 + ww] = f2b(a1 + bv);
  yo[(hh0 + 2) * 32 + ww] = f2b(a2 + bv);
  yo[(hh0 + 3) * 32 + ww] = f2b(a3 + bv);
}

// LayerNorm over C=384 + NCHW->NHWC transpose; output in MFMA-fragment-packed
// layout for gemm1's A operand:
//   tn[((m>>4)*12 + (c>>5))*512 + ((m&15) + 16*((c&31)>>3))*8 + (c&7)]
// Block per (b,h) handles m = bh*32..+31 (2 m-blocks x 12 k-blocks = 24 frags).
__global__ __launch_bounds__(256) void k_lnT(const ushort_t* __restrict__ y,
                                             const float* __restrict__ lw,
                                             const float* __restrict__ lb,
                                             ushort_t* __restrict__ t) {
  __shared__ ushort_t tl[32 * 392];
  __shared__ float rsum[8][32], rsq[8][32];
  __shared__ float smu[32], srs[32];
  int bh = blockIdx.x;
  int b = bh >> 5, h = bh & 31;
  int tid = threadIdx.x;
  int w = tid & 31, cg = tid >> 5;
  const ushort_t* base = y + ((size_t)b * 384) * 1024 + h * 32 + w;
  float v[48];
  float s1 = 0.f, s2 = 0.f;
#pragma unroll
  for (int k = 0; k < 48; ++k) {
    int c = cg * 48 + k;
    float f = b2f(base[(size_t)c * 1024]);
    v[k] = f; s1 += f; s2 += f * f;
  }
  rsum[cg][w] = s1; rsq[cg][w] = s2;
  __syncthreads();
  if (tid < 32) {
    float a = 0.f, q = 0.f;
#pragma unroll
    for (int g = 0; g < 8; ++g) { a += rsum[g][tid]; q += rsq[g][tid]; }
    float mu = a * (1.f / 384.f);
    float var = q * (1.f / 384.f) - mu * mu;
    smu[tid] = mu; srs[tid] = rsqrtf(var + 1e-6f);
  }
  __syncthreads();
  float mu = smu[w], rs = srs[w];
#pragma unroll
  for (int k = 0; k < 48; ++k) {
    int c = cg * 48 + k;
    tl[w * 392 + c] = f2b((v[k] - mu) * rs * lw[c] + lb[c]);
  }
  __syncthreads();
  // packed write: frag fragL = (w>>4)*12 + kb, lane holds (w&15, k-oct)
  ushort_t* obase = t + (size_t)bh * 12288;  // 24 frags * 512 ushorts
#pragma unroll
  for (int i = 0; i < 6; ++i) {
    int flat = i * 256 + tid;          // [0,1536)
    int fragL = flat >> 6;             // 0..23
    int ln = flat & 63;
    int wv = (fragL / 12) * 16 + (ln & 15);
    int cc = (fragL % 12) * 32 + (ln >> 4) * 8;
    *(uint4*)(obase + (size_t)fragL * 512 + ln * 8) =
        *(const uint4*)(tl + wv * 392 + cc);
  }
}

__device__ __forceinline__ void gl_lds16(const void* g, void* l) {
  __builtin_amdgcn_global_load_lds(
      (const __attribute__((address_space(1))) unsigned int*)g,
      (__attribute__((address_space(3))) unsigned int*)l, 16, 0, 0);
}

// ---------------- GEMM1 ----------------
// hid[m,n] = gelu(A[M,384] @ W1[1536,384]^T + bias)
// Tile 256m x 64n, 4 waves (wm = wid*64, shared 64-n panel).
// A: fragment-packed global -> register, depth-1 ping-pong prefetch
//    (one coalesced 1KB global_load_dwordx4 per frag).
// B: 64x32 per step via 3-buffer global_load_lds (12KB LDS), XOR-swizzled.
// Counted s_waitcnt vmcnt(1): batch order per step = [A(t+1) x4][B(t+2) x1],
// pinned with sched_barrier, ONE s_barrier per step.
template <int T>
__device__ __forceinline__ void g1_step(const ushort_t* Ab, const ushort_t* Bg,
                                        ushort_t (*Bs)[2048], int wid, int l16,
                                        int quadA,
                                        bf16x8 (&afC)[4], bf16x8 (&afN)[4],
                                        f32x4 (&acc)[4][4]) {
  if (T < 11) asm volatile("s_waitcnt vmcnt(1)" ::: "memory");
  else        asm volatile("s_waitcnt vmcnt(0)" ::: "memory");
  __builtin_amdgcn_s_barrier();
  __builtin_amdgcn_sched_barrier(0);
  if (T + 1 < 12) {
#pragma unroll
    for (int i = 0; i < 4; ++i)
      afN[i] = *(const bf16x8*)(Ab + (size_t)i * 6144 + (T + 1) * 512);
  }
  __builtin_amdgcn_sched_barrier(0);
  if (T + 2 < 12)
    gl_lds16(Bg + (T + 2) * 32, Bs[(T + 2) % 3] + wid * 512);
  __builtin_amdgcn_sched_barrier(0);
  bf16x8 bfr[4];
#pragma unroll
  for (int j = 0; j < 4; ++j)
    bfr[j] = *(const bf16x8*)(Bs[T % 3] + (j * 16 + l16) * 32 + quadA * 8);
#pragma unroll
  for (int i = 0; i < 4; ++i)
#pragma unroll
    for (int j = 0; j < 4; ++j)  // swapped operands -> transposed D
      acc[i][j] = __builtin_amdgcn_mfma_f32_16x16x32_bf16(bfr[j], afC[i],
                                                          acc[i][j], 0, 0, 0);
}

__global__ __launch_bounds__(256) void k_gemm1(const ushort_t* __restrict__ Ap,
                                               const ushort_t* __restrict__ Bp,
                                               const float* __restrict__ bias,
                                               ushort_t* __restrict__ out) {
  const int N = 1536;
  const int K = 384;
  __shared__ ushort_t Bs[3][2048];
  const int tid = threadIdx.x;
  const int wid = tid >> 6;
  const int lane = tid & 63;
  const int quad = lane >> 4;
  const int l16 = lane & 15;
  int lin = blockIdx.y * 24 + blockIdx.x;
  const int cpx = (24 * (int)gridDim.y) >> 3;  // nwg/8, nwg%8==0
  lin = (lin & 7) * cpx + (lin >> 3);
  const int m0 = (lin / 24) * 256;
  const int n0 = (lin % 24) * 64;
  const int row = tid >> 2;                    // B panel row 0..63
  const int seg = (tid & 3) ^ ((tid >> 3) & 3);
  const int quadA = quad ^ ((l16 >> 1) & 3);
  const ushort_t* Bg = Bp + (size_t)(n0 + row) * K + seg * 8;
  const ushort_t* Ab = Ap + ((size_t)((m0 + wid * 64) >> 4) * 12) * 512 + lane * 8;
  f32x4 acc[4][4] = {};
  bf16x8 afA[4], afB[4];
  // prologue, issue order: B0, A0 x4, B1  (top of step0 waits vmcnt(1))
  gl_lds16(Bg, Bs[0] + wid * 512);
  __builtin_amdgcn_sched_barrier(0);
#pragma unroll
  for (int i = 0; i < 4; ++i)
    afA[i] = *(const bf16x8*)(Ab + (size_t)i * 6144);
  __builtin_amdgcn_sched_barrier(0);
  gl_lds16(Bg + 32, Bs[1] + wid * 512);
  __builtin_amdgcn_sched_barrier(0);
  g1_step<0>(Ab, Bg, Bs, wid, l16, quadA, afA, afB, acc);
  g1_step<1>(Ab, Bg, Bs, wid, l16, quadA, afB, afA, acc);
  g1_step<2>(Ab, Bg, Bs, wid, l16, quadA, afA, afB, acc);
  g1_step<3>(Ab, Bg, Bs, wid, l16, quadA, afB, afA, acc);
  g1_step<4>(Ab, Bg, Bs, wid, l16, quadA, afA, afB, acc);
  g1_step<5>(Ab, Bg, Bs, wid, l16, quadA, afB, afA, acc);
  g1_step<6>(Ab, Bg, Bs, wid, l16, quadA, afA, afB, acc);
  g1_step<7>(Ab, Bg, Bs, wid, l16, quadA, afB, afA, acc);
  g1_step<8>(Ab, Bg, Bs, wid, l16, quadA, afA, afB, acc);
  g1_step<9>(Ab, Bg, Bs, wid, l16, quadA, afB, afA, acc);
  g1_step<10>(Ab, Bg, Bs, wid, l16, quadA, afA, afB, acc);
  g1_step<11>(Ab, Bg, Bs, wid, l16, quadA, afB, afA, acc);
  // epilogue: lane holds m = m0+wid*64+i*16+l16, n = n0+j*16+quad*4+r
  const size_t mrow = (size_t)(m0 + wid * 64 + l16) * N;
#pragma unroll
  for (int j = 0; j < 4; ++j) {
    const int nbg = n0 + j * 16 + quad * 4;
    const float4 bv = *(const float4*)(bias + nbg);
#pragma unroll
    for (int i = 0; i < 4; ++i) {
      float v0 = fgelu(acc[i][j][0] + bv.x);
      float v1 = fgelu(acc[i][j][1] + bv.y);
      float v2 = fgelu(acc[i][j][2] + bv.z);
      float v3 = fgelu(acc[i][j][3] + bv.w);
      unsigned lo, hi;
      asm("v_cvt_pk_bf16_f32 %0, %1, %2" : "=v"(lo) : "v"(v0), "v"(v1));
      asm("v_cvt_pk_bf16_f32 %0, %1, %2" : "=v"(hi) : "v"(v2), "v"(v3));
      *(uint2*)(out + mrow + (size_t)(i * 16) * N + nbg) = make_uint2(lo, hi);
    }
  }
}

// GEMM2 + fused residual: out[b,c,sp] = x + (A@Bt^T + b2)*gamma, NCHW via LDS
// 3-buffer counted-vmcnt pipeline; epilogue transpose buffer aliased
__global__ __launch_bounds__(256) void k_gemm2(const ushort_t* __restrict__ A,
                                               const ushort_t* __restrict__ Bt,
                                               const float* __restrict__ bias,
                                               const float* __restrict__ scale,
                                               const float* __restrict__ x,
                                               float* __restrict__ out,
                                               int mbase) {
  const int K = 1536;
  const int nt = 48;
  __shared__ __align__(16) char smem[49152];
  ushort_t* AsB = (ushort_t*)smem;        // 3 x 4096 ushorts
  ushort_t* BsB = AsB + 12288;            // 3 x 4096 ushorts
  float* tb = (float*)smem;               // epilogue transpose (aliased, 33792B)
  const int tid = threadIdx.x;
  const int wid = tid >> 6;
  const int lane = tid & 63;
  const int quad = lane >> 4;
  const int l16 = lane & 15;
  int lin = blockIdx.y * 3 + blockIdx.x;
  const int cpx = (3 * (int)gridDim.y) >> 3;
  lin = (lin & 7) * cpx + (lin >> 3);
  const int m0 = (lin / 3) * 128;
  const int n0 = (lin % 3) * 128;
  const int wm = (wid & 1) * 64;
  const int wn = (wid >> 1) * 64;
  const int row = tid >> 2;
  const int seg = (tid & 3) ^ ((tid >> 3) & 3);
  const int quadA = quad ^ ((l16 >> 1) & 3);
  const ushort_t* Ag0 = A + (size_t)(m0 + row) * K + seg * 8;
  const ushort_t* Ag1 = Ag0 + (size_t)64 * K;
  const ushort_t* Bg0 = Bt + (size_t)(n0 + row) * K + seg * 8;
  const ushort_t* Bg1 = Bg0 + (size_t)64 * K;
  const int wo = wid * 512;
  f32x4 acc[4][4] = {};
  // prologue
  gl_lds16(Ag0, AsB + wo);
  gl_lds16(Ag1, AsB + wo + 2048);
  gl_lds16(Bg0, BsB + wo);
  gl_lds16(Bg1, BsB + wo + 2048);
  gl_lds16(Ag0 + 32, AsB + 4096 + wo);
  gl_lds16(Ag1 + 32, AsB + 4096 + wo + 2048);
  gl_lds16(Bg0 + 32, BsB + 4096 + wo);
  gl_lds16(Bg1 + 32, BsB + 4096 + wo + 2048);
  int rb = 0, wb = 2;
  for (int t = 0; t < nt - 1; ++t) {
    asm volatile("s_waitcnt vmcnt(4)" ::: "memory");
    __builtin_amdgcn_s_barrier();
    __builtin_amdgcn_sched_barrier(0);
    if (t < nt - 2) {
      const int k2 = (t + 2) << 5;
      ushort_t* Asn = AsB + wb * 4096;
      ushort_t* Bsn = BsB + wb * 4096;
      gl_lds16(Ag0 + k2, Asn + wo);
      gl_lds16(Ag1 + k2, Asn + wo + 2048);
      gl_lds16(Bg0 + k2, Bsn + wo);
      gl_lds16(Bg1 + k2, Bsn + wo + 2048);
    }
    const ushort_t* Asc = AsB + rb * 4096;
    const ushort_t* Bsc = BsB + rb * 4096;
    bf16x8 af[4], bfr[4];
#pragma unroll
    for (int i = 0; i < 4; ++i)
      af[i] = *(const bf16x8*)(Asc + (wm + i * 16 + l16) * 32 + quadA * 8);
#pragma unroll
    for (int j = 0; j < 4; ++j)
      bfr[j] = *(const bf16x8*)(Bsc + (wn + j * 16 + l16) * 32 + quadA * 8);
#pragma unroll
    for (int i = 0; i < 4; ++i)
#pragma unroll
      for (int j = 0; j < 4; ++j)
        acc[i][j] = __builtin_amdgcn_mfma_f32_16x16x32_bf16(af[i], bfr[j], acc[i][j], 0, 0, 0);
    rb = (rb == 2) ? 0 : rb + 1;
    wb = (wb == 2) ? 0 : wb + 1;
  }
  // final tile
  asm volatile("s_waitcnt vmcnt(0)" ::: "memory");
  __builtin_amdgcn_s_barrier();
  __builtin_amdgcn_sched_barrier(0);
  {
    const ushort_t* Asc = AsB + rb * 4096;
    const ushort_t* Bsc = BsB + rb * 4096;
    bf16x8 af[4], bfr[4];
#pragma unroll
    for (int i = 0; i < 4; ++i)
      af[i] = *(const bf16x8*)(Asc + (wm + i * 16 + l16) * 32 + quadA * 8);
#pragma unroll
    for (int j = 0; j < 4; ++j)
      bfr[j] = *(const bf16x8*)(Bsc + (wn + j * 16 + l16) * 32 + quadA * 8);
#pragma unroll
    for (int i = 0; i < 4; ++i)
#pragma unroll
      for (int j = 0; j < 4; ++j)
        acc[i][j] = __builtin_amdgcn_mfma_f32_16x16x32_bf16(af[i], bfr[j], acc[i][j], 0, 0, 0);
  }
  const int mg = mbase + m0;
  const int b = mg >> 10;
  const int sp0 = mg & 1023;
#pragma unroll
  for (int p = 0; p < 2; ++p) {
    __syncthreads();
    if ((wid >> 1) == p) {
#pragma unroll
      for (int j = 0; j < 4; ++j) {
        int nl = j * 16 + l16;
        int cch = n0 + p * 64 + nl;
        float bv = bias[cch], sv = scale[cch];
#pragma unroll
        for (int i = 0; i < 4; ++i) {
          int ml = wm + i * 16 + quad * 4;
          *(float4*)(tb + nl * 132 + ml) = make_float4(
              (acc[i][j][0] + bv) * sv, (acc[i][j][1] + bv) * sv,
              (acc[i][j][2] + bv) * sv, (acc[i][j][3] + bv) * sv);
        }
      }
    }
    __syncthreads();
#pragma unroll
    for (int q = 0; q < 8; ++q) {
      int flat4 = q * 256 + tid;
      int cl = flat4 >> 5;
      int m4 = (flat4 & 31) << 2;
      size_t ga = (((size_t)b * 384 + n0 + p * 64 + cl) << 10) + sp0 + m4;
      float4 xv = *(const float4*)(x + ga);
      float4 tv = *(const float4*)(tb + cl * 132 + m4);
      *(float4*)(out + ga) = make_float4(xv.x + tv.x, xv.y + tv.y,
                                         xv.z + tv.z, xv.w + tv.w);
    }
  }
}

extern "C" void kernel_launch(void* const* d_in, const int* in_sizes, int n_in,
                              void* d_out, int out_size, void* d_ws, size_t ws_size,
                              hipStream_t stream) {
  const float* x        = (const float*)d_in[0];
  const float* kp_w1    = (const float*)d_in[1];
  const float* bn_gamma = (const float*)d_in[2];
  const float* bn_beta  = (const float*)d_in[3];
  const float* bn_mean  = (const float*)d_in[4];
  const float* bn_var   = (const float*)d_in[5];
  const float* kp_w2    = (const float*)d_in[6];
  const float* kp_b2    = (const float*)d_in[7];
  const float* fn_std   = (const float*)d_in[8];
  const float* fn_mean  = (const float*)d_in[9];
  const float* bias     = (const float*)d_in[10];
  const float* ln_w     = (const float*)d_in[11];
  const float* ln_b     = (const float*)d_in[12];
  const float* w1       = (const float*)d_in[13];
  const float* b1       = (const float*)d_in[14];
  const float* w2       = (const float*)d_in[15];
  const float* b2       = (const float*)d_in[16];
  const float* gamma    = (const float*)d_in[17];
  float* out = (float*)d_out;

  char* ws = (char*)d_ws;
  float*    praw   = (float*)(ws + 0);            // 6291456
  float*    pB     = (float*)(ws + 6291456);      // 98304
  float*    hbuf   = (float*)(ws + 6389760);      // 6144
  float2*   part   = (float2*)(ws + 6395904);     // 49152
  float2*   stats  = (float2*)(ws + 6445056);     // 512
  ushort_t* w1b    = (ushort_t*)(ws + 6445568);   // 1179648 (fragment-packed)
  ushort_t* w2b    = (ushort_t*)(ws + 7625216);   // 1179648
  ushort_t* ybuf   = (ushort_t*)(ws + 8804864);   // 50331648
  ushort_t* tn     = (ushort_t*)(ws + 59136512);  // 50331648 (fragment-packed)
  ushort_t* hid    = (ushort_t*)(ws + 109468160); // up to 201326592

  // chunking: hid for M-rows/chunk of the 65536-row MLP
  int nchunks;
  if (ws_size >= 310794752ULL) nchunks = 1;
  else if (ws_size >= 210131456ULL) nchunks = 2;
  else nchunks = 4;
  int mrows = 65536 / nchunks;

  k_packw1<<<288, 256, 0, stream>>>(w1, w1b);
  k_tobf16<<<2304, 256, 0, stream>>>(w2, w2b, 589824);
  k_pool<<<6144, 256, 0, stream>>>(x, pB);
  k_h<<<dim3(24, 64), 64, 0, stream>>>(pB, kp_w1, bn_gamma, bn_beta, bn_mean,
                                       bn_var, hbuf);
  k_praw<<<dim3(96, 64), 256, 0, stream>>>(hbuf, kp_w2, kp_b2, praw, part);
  k_pstat<<<64, 128, 0, stream>>>(part, stats);
  k_conv<<<dim3(384, 64), 256, 0, stream>>>(x, praw, stats, fn_std, fn_mean,
                                            bias, ybuf);
  k_lnT<<<2048, 256, 0, stream>>>(ybuf, ln_w, ln_b, tn);
  for (int s = 0; s < nchunks; ++s) {
    k_gemm1<<<dim3(24, mrows / 256), 256, 0, stream>>>(
        tn + (size_t)s * mrows * 384, w1b, b1, hid);
    k_gemm2<<<dim3(3, mrows / 128), 256, 0, stream>>>(
        hid, w2b, b2, gamma, x, out, s * mrows);
  }
}

// Round 5
// 393.231 us; speedup vs baseline: 1.1423x; 1.0513x over previous
//
#include <hip/hip_runtime.h>
#include <cstdint>

typedef unsigned short ushort_t;
typedef __bf16 bf16x8 __attribute__((ext_vector_type(8)));
typedef float f32x4 __attribute__((ext_vector_type(4)));

__device__ __forceinline__ ushort_t f2b(float f) {
  union { float f; unsigned u; } v; v.f = f;
  unsigned u = v.u;
  return (ushort_t)((u + 0x7FFFu + ((u >> 16) & 1u)) >> 16);
}
__device__ __forceinline__ float b2f(ushort_t h) {
  union { unsigned u; float f; } v; v.u = ((unsigned)h) << 16;
  return v.f;
}

// fast sigmoid-gelu: v * rcp(1 + exp(-1.702 v)); error suppressed by gamma=1e-6
__device__ __forceinline__ float fgelu(float v) {
  float e = __expf(v * -1.702f);
  return v * __builtin_amdgcn_rcpf(1.0f + e);
}

// f32 -> bf16 cast for weights
__global__ __launch_bounds__(256) void k_tobf16(const float* __restrict__ s,
                                                ushort_t* __restrict__ d, int n) {
  int i = blockIdx.x * 256 + threadIdx.x;
  if (i < n) d[i] = f2b(s[i]);
}

// p[b,c] = mean over 32x32 spatial; one wave per (b,c)
__global__ __launch_bounds__(256) void k_pool(const float* __restrict__ x,
                                              float* __restrict__ p) {
  int wid = threadIdx.x >> 6, lane = threadIdx.x & 63;
  int bc = blockIdx.x * 4 + wid;
  const float4* xr = (const float4*)(x + (size_t)bc * 1024);
  float s = 0.f;
#pragma unroll
  for (int i = 0; i < 4; ++i) {
    float4 t = xr[i * 64 + lane];
    s += (t.x + t.y) + (t.z + t.w);
  }
#pragma unroll
  for (int off = 32; off > 0; off >>= 1) s += __shfl_down(s, off);
  if (lane == 0) p[bc] = s * (1.0f / 1024.0f);
}

// h[b][o] = relu(bn(p[b] . kp_w1[o])); one wave per (o,b); grid (24,64), block 64
__global__ __launch_bounds__(64) void k_h(
    const float* __restrict__ p, const float* __restrict__ kp_w1,
    const float* __restrict__ bn_gamma, const float* __restrict__ bn_beta,
    const float* __restrict__ bn_mean, const float* __restrict__ bn_var,
    float* __restrict__ hbuf) {
  int o = blockIdx.x, b = blockIdx.y, lane = threadIdx.x;
  const float* pr = p + b * 384;
  const float* wr = kp_w1 + o * 384;
  float s = 0.f;
#pragma unroll
  for (int i = 0; i < 6; ++i) {
    int c = i * 64 + lane;
    s += pr[c] * wr[c];
  }
#pragma unroll
  for (int off = 32; off > 0; off >>= 1) s += __shfl_down(s, off);
  if (lane == 0) {
    float a = (s - bn_mean[o]) * rsqrtf(bn_var[o] + 1e-5f) * bn_gamma[o] + bn_beta[o];
    hbuf[b * 24 + o] = fmaxf(a, 0.f);
  }
}

// praw[b][j] = h[b].kp_w2[j] + kp_b2[j]; per-block partial sums -> part[b][bx]
// grid (96, 64), block 256
__global__ __launch_bounds__(256) void k_praw(
    const float* __restrict__ hbuf, const float* __restrict__ kp_w2,
    const float* __restrict__ kp_b2, float* __restrict__ praw,
    float2* __restrict__ part) {
  __shared__ float wrow[256 * 25];
  __shared__ float hs[24];
  __shared__ float r1[256], r2[256];
  int bx = blockIdx.x, b = blockIdx.y, tid = threadIdx.x;
  int j0 = bx * 256;
  for (int t = tid; t < 6144; t += 256) {
    int row = t / 24, col = t - row * 24;
    wrow[row * 25 + col] = kp_w2[(size_t)j0 * 24 + t];
  }
  if (tid < 24) hs[tid] = hbuf[b * 24 + tid];
  __syncthreads();
  float a = kp_b2[j0 + tid];
  const float* wr = wrow + tid * 25;
#pragma unroll
  for (int r = 0; r < 24; ++r) a += hs[r] * wr[r];
  praw[(size_t)b * 24576 + j0 + tid] = a;
  r1[tid] = a; r2[tid] = a * a;
  __syncthreads();
  for (int off = 128; off > 0; off >>= 1) {
    if (tid < off) { r1[tid] += r1[tid + off]; r2[tid] += r2[tid + off]; }
    __syncthreads();
  }
  if (tid == 0) part[b * 96 + bx] = make_float2(r1[0], r2[0]);
}

// stats[b] = (u, rsqrt(var)); grid 64, block 128 (96 active)
__global__ __launch_bounds__(128) void k_pstat(const float2* __restrict__ part,
                                               float2* __restrict__ stats) {
  __shared__ float r1[128], r2[128];
  int b = blockIdx.x, tid = threadIdx.x;
  float2 v = (tid < 96) ? part[b * 96 + tid] : make_float2(0.f, 0.f);
  r1[tid] = v.x; r2[tid] = v.y;
  __syncthreads();
  for (int off = 64; off > 0; off >>= 1) {
    if (tid < off) { r1[tid] += r1[tid + off]; r2[tid] += r2[tid + off]; }
    __syncthreads();
  }
  if (tid == 0) {
    float u = r1[0] * (1.f / 24576.f);
    float var = r2[0] * (1.f / 24576.f) - u * u;
    stats[b] = make_float2(u, rsqrtf(var + 1e-12f));
  }
}

// circulant conv per (b,c); writes y NCHW bf16 = conv + bias.
// Frame-norm affine applied on param load. grid (384, 64)
__global__ __launch_bounds__(256) void k_conv(const float* __restrict__ x,
                                              const float* __restrict__ praw,
                                              const float2* __restrict__ stats,
                                              const float* __restrict__ fn_std,
                                              const float* __restrict__ fn_mean,
                                              const float* __restrict__ bias,
                                              ushort_t* __restrict__ y) {
  __shared__ float xs[1024];
  __shared__ float pe[32];
  __shared__ float kn[32];
  int c = blockIdx.x, b = blockIdx.y;
  int tid = threadIdx.x;
  size_t plane = ((size_t)b * 384 + c) * 1024;
  float4 xv = ((const float4*)(x + plane))[tid];
  if (tid < 32) {
    float2 st = stats[b];
    int j1 = c * 32 + tid;
    int j2 = (384 + c) * 32 + tid;
    pe[tid] = (praw[(size_t)b * 24576 + j1] - st.x) * st.y * fn_std[j1] + fn_mean[j1];
    kn[tid] = (praw[(size_t)b * 24576 + j2] - st.x) * st.y * fn_std[j2] + fn_mean[j2];
  }
  __syncthreads();
  const bool hm = (c < 192);
  {
    int e0 = tid * 4;
    float4 t;
    if (hm) {
      float pv = pe[e0 >> 5];
      t.x = xv.x + pv; t.y = xv.y + pv; t.z = xv.z + pv; t.w = xv.w + pv;
    } else {
      int w0 = e0 & 31;
      t.x = xv.x + pe[w0]; t.y = xv.y + pe[w0 + 1];
      t.z = xv.z + pe[w0 + 2]; t.w = xv.w + pe[w0 + 3];
    }
    *(float4*)(xs + e0) = t;
  }
  __syncthreads();
  int ww = tid & 31, hh0 = (tid >> 5) * 4;
  float a0 = 0, a1 = 0, a2 = 0, a3 = 0;
  if (hm) {
    float c0 = xs[hh0 * 32 + ww], c1 = xs[(hh0 + 1) * 32 + ww];
    float c2 = xs[(hh0 + 2) * 32 + ww], c3 = xs[(hh0 + 3) * 32 + ww];
#pragma unroll
    for (int d = 0; d < 32; ++d) {
      float kv = kn[d];
      a0 += kv * c0; a1 += kv * c1; a2 += kv * c2; a3 += kv * c3;
      c0 = c1; c1 = c2; c2 = c3;
      c3 = xs[(((hh0 + d + 4) & 31) << 5) + ww];
    }
  } else {
#pragma unroll
    for (int d = 0; d < 32; ++d) {
      float kv = kn[d];
      int wc = (ww + d) & 31;
      a0 += kv * xs[(hh0    ) * 32 + wc];
      a1 += kv * xs[(hh0 + 1) * 32 + wc];
      a2 += kv * xs[(hh0 + 2) * 32 + wc];
      a3 += kv * xs[(hh0 + 3) * 32 + wc];
    }
  }
  float bv = bias[c];
  ushort_t* yo = y + plane;
  yo[(hh0    ) * 32 + ww] = f2b(a0 + bv);
  yo[(hh0 + 1) * 32 + ww] = f2b(a1 + bv);
  yo[(hh0 + 2) * 32 + ww] = f2b(a2 + bv);
  yo[(hh0 + 3) * 32 + ww] = f2b(a3 + bv);
}

// LayerNorm over C=384 + NCHW->NHWC transpose. Block per (b,h); out NHWC bf16.
__global__ __launch_bounds__(256) void k_lnT(const ushort_t* __restrict__ y,
                                             const float* __restrict__ lw,
                                             const float* __restrict__ lb,
                                             ushort_t* __restrict__ t) {
  __shared__ ushort_t tl[32 * 392];
  __shared__ float rsum[8][32], rsq[8][32];
  __shared__ float smu[32], srs[32];
  int bh = blockIdx.x;
  int b = bh >> 5, h = bh & 31;
  int tid = threadIdx.x;
  int w = tid & 31, cg = tid >> 5;
  const ushort_t* base = y + ((size_t)b * 384) * 1024 + h * 32 + w;
  float v[48];
  float s1 = 0.f, s2 = 0.f;
#pragma unroll
  for (int k = 0; k < 48; ++k) {
    int c = cg * 48 + k;
    float f = b2f(base[(size_t)c * 1024]);
    v[k] = f; s1 += f; s2 += f * f;
  }
  rsum[cg][w] = s1; rsq[cg][w] = s2;
  __syncthreads();
  if (tid < 32) {
    float a = 0.f, q = 0.f;
#pragma unroll
    for (int g = 0; g < 8; ++g) { a += rsum[g][tid]; q += rsq[g][tid]; }
    float mu = a * (1.f / 384.f);
    float var = q * (1.f / 384.f) - mu * mu;
    smu[tid] = mu; srs[tid] = rsqrtf(var + 1e-6f);
  }
  __syncthreads();
  float mu = smu[w], rs = srs[w];
#pragma unroll
  for (int k = 0; k < 48; ++k) {
    int c = cg * 48 + k;
    tl[w * 392 + c] = f2b((v[k] - mu) * rs * lw[c] + lb[c]);
  }
  __syncthreads();
  ushort_t* orow = t + (size_t)bh * 32 * 384;
#pragma unroll
  for (int i = 0; i < 6; ++i) {
    int flat16 = i * 256 + tid;
    int ww = flat16 / 48, c8 = flat16 % 48;
    *(uint4*)(orow + ww * 384 + c8 * 8) = *(const uint4*)(tl + ww * 392 + c8 * 8);
  }
}

__device__ __forceinline__ void gl_lds16(const void* g, void* l) {
  __builtin_amdgcn_global_load_lds(
      (const __attribute__((address_space(1))) unsigned int*)g,
      (__attribute__((address_space(3))) unsigned int*)l, 16, 0, 0);
}

// ---------------- GEMM1 ----------------
// hid[m,n] = gelu(A[M,384] @ W1[1536,384]^T + bias); tile 256m x 128n, 8 waves
// (wave-tile 64x64, 4m x 2n), BK=32, 3-buffer LDS, counted vmcnt(3),
// 3 staging calls/step (A x2 @512thr, B x1), XOR swizzle, transposed acc,
// XCD-chunked swizzle. 72KB LDS -> 2 blocks/CU; launch_bounds(512,4).
__global__ __launch_bounds__(512, 4) void k_gemm1(const ushort_t* __restrict__ A,
                                                  const ushort_t* __restrict__ Bt,
                                                  const float* __restrict__ bias,
                                                  ushort_t* __restrict__ out) {
  const int N = 1536;
  const int K = 384;
  __shared__ ushort_t As[3][8192];
  __shared__ ushort_t Bs[3][4096];
  const int tid = threadIdx.x;
  const int wid = tid >> 6;
  const int lane = tid & 63;
  const int quad = lane >> 4;
  const int l16 = lane & 15;
  int lin = blockIdx.y * 12 + blockIdx.x;
  const int cpx = (12 * (int)gridDim.y) >> 3;  // nwg/8, nwg%8==0
  lin = (lin & 7) * cpx + (lin >> 3);
  const int m0 = (lin / 12) * 256;
  const int n0 = (lin % 12) * 128;
  const int wm = (wid & 3) * 64;
  const int wn = (wid >> 2) * 64;
  const int row = tid >> 2;                    // 0..127
  const int seg = (tid & 3) ^ ((tid >> 3) & 3);
  const int quadA = quad ^ ((l16 >> 1) & 3);
  const ushort_t* Ag0 = A + (size_t)(m0 + row) * K + seg * 8;   // rows 0..127
  const ushort_t* Ag1 = Ag0 + (size_t)128 * K;                  // rows 128..255
  const ushort_t* Bg  = Bt + (size_t)(n0 + row) * K + seg * 8;  // 128 rows
  const int wo = wid * 512;
  f32x4 acc[4][4] = {};
  // prologue: tiles 0,1 (6 calls in flight)
  gl_lds16(Ag0, As[0] + wo);
  gl_lds16(Ag1, As[0] + 4096 + wo);
  gl_lds16(Bg,  Bs[0] + wo);
  gl_lds16(Ag0 + 32, As[1] + wo);
  gl_lds16(Ag1 + 32, As[1] + 4096 + wo);
  gl_lds16(Bg + 32,  Bs[1] + wo);
#pragma unroll
  for (int t = 0; t < 12; ++t) {
    if (t < 11) asm volatile("s_waitcnt vmcnt(3)" ::: "memory");
    else        asm volatile("s_waitcnt vmcnt(0)" ::: "memory");
    __builtin_amdgcn_s_barrier();
    __builtin_amdgcn_sched_barrier(0);
    if (t + 2 < 12) {
      const int k2 = (t + 2) * 32;
      const int b2 = (t + 2) % 3;
      gl_lds16(Ag0 + k2, As[b2] + wo);
      gl_lds16(Ag1 + k2, As[b2] + 4096 + wo);
      gl_lds16(Bg + k2,  Bs[b2] + wo);
    }
    const ushort_t* Asc = As[t % 3];
    const ushort_t* Bsc = Bs[t % 3];
    bf16x8 af[4], bfr[4];
#pragma unroll
    for (int i = 0; i < 4; ++i)
      af[i] = *(const bf16x8*)(Asc + (wm + i * 16 + l16) * 32 + quadA * 8);
#pragma unroll
    for (int j = 0; j < 4; ++j)
      bfr[j] = *(const bf16x8*)(Bsc + (wn + j * 16 + l16) * 32 + quadA * 8);
#pragma unroll
    for (int i = 0; i < 4; ++i)
#pragma unroll
      for (int j = 0; j < 4; ++j)   // swapped operands -> transposed D
        acc[i][j] = __builtin_amdgcn_mfma_f32_16x16x32_bf16(bfr[j], af[i],
                                                            acc[i][j], 0, 0, 0);
  }
  // epilogue: lane holds m = m0+wm+i*16+l16, n = n0+wn+j*16+quad*4+r
  const size_t mrow = (size_t)(m0 + wm + l16) * N;
#pragma unroll
  for (int j = 0; j < 4; ++j) {
    const int nbg = n0 + wn + j * 16 + quad * 4;
    const float4 bv = *(const float4*)(bias + nbg);
#pragma unroll
    for (int i = 0; i < 4; ++i) {
      float v0 = fgelu(acc[i][j][0] + bv.x);
      float v1 = fgelu(acc[i][j][1] + bv.y);
      float v2 = fgelu(acc[i][j][2] + bv.z);
      float v3 = fgelu(acc[i][j][3] + bv.w);
      unsigned lo, hi;
      asm("v_cvt_pk_bf16_f32 %0, %1, %2" : "=v"(lo) : "v"(v0), "v"(v1));
      asm("v_cvt_pk_bf16_f32 %0, %1, %2" : "=v"(hi) : "v"(v2), "v"(v3));
      *(uint2*)(out + mrow + (size_t)(i * 16) * N + nbg) = make_uint2(lo, hi);
    }
  }
}

// ---------------- GEMM2 + fused residual ----------------
// out[b,c,sp] = x + (A@Bt^T + b2)*gamma, NCHW; tile 256m x 128n, 8 waves,
// same 3-buffer counted-vmcnt pipeline; 2-phase 64x260f transpose epilogue
// aliased over the 72KB staging LDS.
__global__ __launch_bounds__(512, 4) void k_gemm2(const ushort_t* __restrict__ A,
                                                  const ushort_t* __restrict__ Bt,
                                                  const float* __restrict__ bias,
                                                  const float* __restrict__ scale,
                                                  const float* __restrict__ x,
                                                  float* __restrict__ out,
                                                  int mbase) {
  const int K = 1536;
  const int nt = 48;
  __shared__ __align__(16) char smem[73728];
  ushort_t* AsB = (ushort_t*)smem;        // 3 x 8192 ushorts
  ushort_t* BsB = AsB + 24576;            // 3 x 4096 ushorts
  float* tb = (float*)smem;               // epilogue 64x260 floats (aliased)
  const int tid = threadIdx.x;
  const int wid = tid >> 6;
  const int lane = tid & 63;
  const int quad = lane >> 4;
  const int l16 = lane & 15;
  int lin = blockIdx.y * 3 + blockIdx.x;
  const int cpx = (3 * (int)gridDim.y) >> 3;
  lin = (lin & 7) * cpx + (lin >> 3);
  const int m0 = (lin / 3) * 256;
  const int n0 = (lin % 3) * 128;
  const int wm = (wid & 3) * 64;
  const int wn = (wid >> 2) * 64;
  const int row = tid >> 2;
  const int seg = (tid & 3) ^ ((tid >> 3) & 3);
  const int quadA = quad ^ ((l16 >> 1) & 3);
  const ushort_t* Ag0 = A + (size_t)(m0 + row) * K + seg * 8;
  const ushort_t* Ag1 = Ag0 + (size_t)128 * K;
  const ushort_t* Bg  = Bt + (size_t)(n0 + row) * K + seg * 8;
  const int wo = wid * 512;
  f32x4 acc[4][4] = {};
  // prologue
  gl_lds16(Ag0, AsB + wo);
  gl_lds16(Ag1, AsB + 4096 + wo);
  gl_lds16(Bg,  BsB + wo);
  gl_lds16(Ag0 + 32, AsB + 8192 + wo);
  gl_lds16(Ag1 + 32, AsB + 8192 + 4096 + wo);
  gl_lds16(Bg + 32,  BsB + 4096 + wo);
  int rb = 0, wb = 2;
  for (int t = 0; t < nt; ++t) {
    if (t < nt - 1) asm volatile("s_waitcnt vmcnt(3)" ::: "memory");
    else            asm volatile("s_waitcnt vmcnt(0)" ::: "memory");
    __builtin_amdgcn_s_barrier();
    __builtin_amdgcn_sched_barrier(0);
    if (t < nt - 2) {
      const int k2 = (t + 2) << 5;
      ushort_t* Asn = AsB + wb * 8192;
      ushort_t* Bsn = BsB + wb * 4096;
      gl_lds16(Ag0 + k2, Asn + wo);
      gl_lds16(Ag1 + k2, Asn + 4096 + wo);
      gl_lds16(Bg + k2,  Bsn + wo);
    }
    const ushort_t* Asc = AsB + rb * 8192;
    const ushort_t* Bsc = BsB + rb * 4096;
    bf16x8 af[4], bfr[4];
#pragma unroll
    for (int i = 0; i < 4; ++i)
      af[i] = *(const bf16x8*)(Asc + (wm + i * 16 + l16) * 32 + quadA * 8);
#pragma unroll
    for (int j = 0; j < 4; ++j)
      bfr[j] = *(const bf16x8*)(Bsc + (wn + j * 16 + l16) * 32 + quadA * 8);
#pragma unroll
    for (int i = 0; i < 4; ++i)
#pragma unroll
      for (int j = 0; j < 4; ++j)
        acc[i][j] = __builtin_amdgcn_mfma_f32_16x16x32_bf16(af[i], bfr[j],
                                                            acc[i][j], 0, 0, 0);
    rb = (rb == 2) ? 0 : rb + 1;
    wb = (wb == 2) ? 0 : wb + 1;
  }
  const int mg = mbase + m0;
  const int b = mg >> 10;
  const int sp0 = mg & 1023;
#pragma unroll
  for (int p = 0; p < 2; ++p) {
    __syncthreads();
    if ((wid >> 2) == p) {   // 4 m-waves of this n-half write acc -> tb
#pragma unroll
      for (int j = 0; j < 4; ++j) {
        int nl = j * 16 + l16;
        int cch = n0 + p * 64 + nl;
        float bv = bias[cch], sv = scale[cch];
#pragma unroll
        for (int i = 0; i < 4; ++i) {
          int ml = wm + i * 16 + quad * 4;
          *(float4*)(tb + nl * 260 + ml) = make_float4(
              (acc[i][j][0] + bv) * sv, (acc[i][j][1] + bv) * sv,
              (acc[i][j][2] + bv) * sv, (acc[i][j][3] + bv) * sv);
        }
      }
    }
    __syncthreads();
#pragma unroll
    for (int q = 0; q < 8; ++q) {
      int flat4 = q * 512 + tid;          // [0,4096): 64 chans x 64 float4
      int cl = flat4 >> 6;
      int m4 = (flat4 & 63) << 2;
      size_t ga = (((size_t)b * 384 + n0 + p * 64 + cl) << 10) + sp0 + m4;
      float4 xv = *(const float4*)(x + ga);
      float4 tv = *(const float4*)(tb + cl * 260 + m4);
      *(float4*)(out + ga) = make_float4(xv.x + tv.x, xv.y + tv.y,
                                         xv.z + tv.z, xv.w + tv.w);
    }
  }
}

extern "C" void kernel_launch(void* const* d_in, const int* in_sizes, int n_in,
                              void* d_out, int out_size, void* d_ws, size_t ws_size,
                              hipStream_t stream) {
  const float* x        = (const float*)d_in[0];
  const float* kp_w1    = (const float*)d_in[1];
  const float* bn_gamma = (const float*)d_in[2];
  const float* bn_beta  = (const float*)d_in[3];
  const float* bn_mean  = (const float*)d_in[4];
  const float* bn_var   = (const float*)d_in[5];
  const float* kp_w2    = (const float*)d_in[6];
  const float* kp_b2    = (const float*)d_in[7];
  const float* fn_std   = (const float*)d_in[8];
  const float* fn_mean  = (const float*)d_in[9];
  const float* bias     = (const float*)d_in[10];
  const float* ln_w     = (const float*)d_in[11];
  const float* ln_b     = (const float*)d_in[12];
  const float* w1       = (const float*)d_in[13];
  const float* b1       = (const float*)d_in[14];
  const float* w2       = (const float*)d_in[15];
  const float* b2       = (const float*)d_in[16];
  const float* gamma    = (const float*)d_in[17];
  float* out = (float*)d_out;

  char* ws = (char*)d_ws;
  float*    praw   = (float*)(ws + 0);            // 6291456
  float*    pB     = (float*)(ws + 6291456);      // 98304
  float*    hbuf   = (float*)(ws + 6389760);      // 6144
  float2*   part   = (float2*)(ws + 6395904);     // 49152
  float2*   stats  = (float2*)(ws + 6445056);     // 512
  ushort_t* w1b    = (ushort_t*)(ws + 6445568);   // 1179648
  ushort_t* w2b    = (ushort_t*)(ws + 7625216);   // 1179648
  ushort_t* ybuf   = (ushort_t*)(ws + 8804864);   // 50331648
  ushort_t* tn     = (ushort_t*)(ws + 59136512);  // 50331648
  ushort_t* hid    = (ushort_t*)(ws + 109468160); // up to 201326592

  // chunking: hid for M-rows/chunk of the 65536-row MLP
  int nchunks;
  if (ws_size >= 310794752ULL) nchunks = 1;
  else if (ws_size >= 210131456ULL) nchunks = 2;
  else nchunks = 4;
  int mrows = 65536 / nchunks;

  k_tobf16<<<2304, 256, 0, stream>>>(w1, w1b, 589824);
  k_tobf16<<<2304, 256, 0, stream>>>(w2, w2b, 589824);
  k_pool<<<6144, 256, 0, stream>>>(x, pB);
  k_h<<<dim3(24, 64), 64, 0, stream>>>(pB, kp_w1, bn_gamma, bn_beta, bn_mean,
                                       bn_var, hbuf);
  k_praw<<<dim3(96, 64), 256, 0, stream>>>(hbuf, kp_w2, kp_b2, praw, part);
  k_pstat<<<64, 128, 0, stream>>>(part, stats);
  k_conv<<<dim3(384, 64), 256, 0, stream>>>(x, praw, stats, fn_std, fn_mean,
                                            bias, ybuf);
  k_lnT<<<2048, 256, 0, stream>>>(ybuf, ln_w, ln_b, tn);
  for (int s = 0; s < nchunks; ++s) {
    k_gemm1<<<dim3(12, mrows / 256), 512, 0, stream>>>(
        tn + (size_t)s * mrows * 384, w1b, b1, hid);
    k_gemm2<<<dim3(3, mrows / 256), 512, 0, stream>>>(
        hid, w2b, b2, gamma, x, out, s * mrows);
  }
}

// Round 6
// 392.113 us; speedup vs baseline: 1.1456x; 1.0028x over previous
//
#include <hip/hip_runtime.h>
#include <cstdint>

typedef unsigned short ushort_t;
typedef __bf16 bf16x8 __attribute__((ext_vector_type(8)));
typedef float f32x4 __attribute__((ext_vector_type(4)));

__device__ __forceinline__ ushort_t f2b(float f) {
  union { float f; unsigned u; } v; v.f = f;
  unsigned u = v.u;
  return (ushort_t)((u + 0x7FFFu + ((u >> 16) & 1u)) >> 16);
}
__device__ __forceinline__ float b2f(ushort_t h) {
  union { unsigned u; float f; } v; v.u = ((unsigned)h) << 16;
  return v.f;
}

// fast sigmoid-gelu: v * rcp(1 + exp(-1.702 v)); error suppressed by gamma=1e-6
__device__ __forceinline__ float fgelu(float v) {
  float e = __expf(v * -1.702f);
  return v * __builtin_amdgcn_rcpf(1.0f + e);
}

// f32 -> bf16 cast for weights
__global__ __launch_bounds__(256) void k_tobf16(const float* __restrict__ s,
                                                ushort_t* __restrict__ d, int n) {
  int i = blockIdx.x * 256 + threadIdx.x;
  if (i < n) d[i] = f2b(s[i]);
}

// p[b,c] = mean over 32x32 spatial; one wave per (b,c)
__global__ __launch_bounds__(256) void k_pool(const float* __restrict__ x,
                                              float* __restrict__ p) {
  int wid = threadIdx.x >> 6, lane = threadIdx.x & 63;
  int bc = blockIdx.x * 4 + wid;
  const float4* xr = (const float4*)(x + (size_t)bc * 1024);
  float s = 0.f;
#pragma unroll
  for (int i = 0; i < 4; ++i) {
    float4 t = xr[i * 64 + lane];
    s += (t.x + t.y) + (t.z + t.w);
  }
#pragma unroll
  for (int off = 32; off > 0; off >>= 1) s += __shfl_down(s, off);
  if (lane == 0) p[bc] = s * (1.0f / 1024.0f);
}

// h[b][o] = relu(bn(p[b] . kp_w1[o])); one wave per (o,b); grid (24,64), block 64
__global__ __launch_bounds__(64) void k_h(
    const float* __restrict__ p, const float* __restrict__ kp_w1,
    const float* __restrict__ bn_gamma, const float* __restrict__ bn_beta,
    const float* __restrict__ bn_mean, const float* __restrict__ bn_var,
    float* __restrict__ hbuf) {
  int o = blockIdx.x, b = blockIdx.y, lane = threadIdx.x;
  const float* pr = p + b * 384;
  const float* wr = kp_w1 + o * 384;
  float s = 0.f;
#pragma unroll
  for (int i = 0; i < 6; ++i) {
    int c = i * 64 + lane;
    s += pr[c] * wr[c];
  }
#pragma unroll
  for (int off = 32; off > 0; off >>= 1) s += __shfl_down(s, off);
  if (lane == 0) {
    float a = (s - bn_mean[o]) * rsqrtf(bn_var[o] + 1e-5f) * bn_gamma[o] + bn_beta[o];
    hbuf[b * 24 + o] = fmaxf(a, 0.f);
  }
}

// praw[b][j] = h[b].kp_w2[j] + kp_b2[j]; per-block partial sums -> part[b][bx]
// grid (96, 64), block 256
__global__ __launch_bounds__(256) void k_praw(
    const float* __restrict__ hbuf, const float* __restrict__ kp_w2,
    const float* __restrict__ kp_b2, float* __restrict__ praw,
    float2* __restrict__ part) {
  __shared__ float wrow[256 * 25];
  __shared__ float hs[24];
  __shared__ float r1[256], r2[256];
  int bx = blockIdx.x, b = blockIdx.y, tid = threadIdx.x;
  int j0 = bx * 256;
  for (int t = tid; t < 6144; t += 256) {
    int row = t / 24, col = t - row * 24;
    wrow[row * 25 + col] = kp_w2[(size_t)j0 * 24 + t];
  }
  if (tid < 24) hs[tid] = hbuf[b * 24 + tid];
  __syncthreads();
  float a = kp_b2[j0 + tid];
  const float* wr = wrow + tid * 25;
#pragma unroll
  for (int r = 0; r < 24; ++r) a += hs[r] * wr[r];
  praw[(size_t)b * 24576 + j0 + tid] = a;
  r1[tid] = a; r2[tid] = a * a;
  __syncthreads();
  for (int off = 128; off > 0; off >>= 1) {
    if (tid < off) { r1[tid] += r1[tid + off]; r2[tid] += r2[tid + off]; }
    __syncthreads();
  }
  if (tid == 0) part[b * 96 + bx] = make_float2(r1[0], r2[0]);
}

// stats[b] = (u, rsqrt(var)); grid 64, block 128 (96 active)
__global__ __launch_bounds__(128) void k_pstat(const float2* __restrict__ part,
                                               float2* __restrict__ stats) {
  __shared__ float r1[128], r2[128];
  int b = blockIdx.x, tid = threadIdx.x;
  float2 v = (tid < 96) ? part[b * 96 + tid] : make_float2(0.f, 0.f);
  r1[tid] = v.x; r2[tid] = v.y;
  __syncthreads();
  for (int off = 64; off > 0; off >>= 1) {
    if (tid < off) { r1[tid] += r1[tid + off]; r2[tid] += r2[tid + off]; }
    __syncthreads();
  }
  if (tid == 0) {
    float u = r1[0] * (1.f / 24576.f);
    float var = r2[0] * (1.f / 24576.f) - u * u;
    stats[b] = make_float2(u, rsqrtf(var + 1e-12f));
  }
}

// circulant conv per (b,c); writes y NCHW bf16 = conv + bias.
// Frame-norm affine applied on param load. grid (384, 64)
__global__ __launch_bounds__(256) void k_conv(const float* __restrict__ x,
                                              const float* __restrict__ praw,
                                              const float2* __restrict__ stats,
                                              const float* __restrict__ fn_std,
                                              const float* __restrict__ fn_mean,
                                              const float* __restrict__ bias,
                                              ushort_t* __restrict__ y) {
  __shared__ float xs[1024];
  __shared__ float pe[32];
  __shared__ float kn[32];
  int c = blockIdx.x, b = blockIdx.y;
  int tid = threadIdx.x;
  size_t plane = ((size_t)b * 384 + c) * 1024;
  float4 xv = ((const float4*)(x + plane))[tid];
  if (tid < 32) {
    float2 st = stats[b];
    int j1 = c * 32 + tid;
    int j2 = (384 + c) * 32 + tid;
    pe[tid] = (praw[(size_t)b * 24576 + j1] - st.x) * st.y * fn_std[j1] + fn_mean[j1];
    kn[tid] = (praw[(size_t)b * 24576 + j2] - st.x) * st.y * fn_std[j2] + fn_mean[j2];
  }
  __syncthreads();
  const bool hm = (c < 192);
  {
    int e0 = tid * 4;
    float4 t;
    if (hm) {
      float pv = pe[e0 >> 5];
      t.x = xv.x + pv; t.y = xv.y + pv; t.z = xv.z + pv; t.w = xv.w + pv;
    } else {
      int w0 = e0 & 31;
      t.x = xv.x + pe[w0]; t.y = xv.y + pe[w0 + 1];
      t.z = xv.z + pe[w0 + 2]; t.w = xv.w + pe[w0 + 3];
    }
    *(float4*)(xs + e0) = t;
  }
  __syncthreads();
  int ww = tid & 31, hh0 = (tid >> 5) * 4;
  float a0 = 0, a1 = 0, a2 = 0, a3 = 0;
  if (hm) {
    float c0 = xs[hh0 * 32 + ww], c1 = xs[(hh0 + 1) * 32 + ww];
    float c2 = xs[(hh0 + 2) * 32 + ww], c3 = xs[(hh0 + 3) * 32 + ww];
#pragma unroll
    for (int d = 0; d < 32; ++d) {
      float kv = kn[d];
      a0 += kv * c0; a1 += kv * c1; a2 += kv * c2; a3 += kv * c3;
      c0 = c1; c1 = c2; c2 = c3;
      c3 = xs[(((hh0 + d + 4) & 31) << 5) + ww];
    }
  } else {
#pragma unroll
    for (int d = 0; d < 32; ++d) {
      float kv = kn[d];
      int wc = (ww + d) & 31;
      a0 += kv * xs[(hh0    ) * 32 + wc];
      a1 += kv * xs[(hh0 + 1) * 32 + wc];
      a2 += kv * xs[(hh0 + 2) * 32 + wc];
      a3 += kv * xs[(hh0 + 3) * 32 + wc];
    }
  }
  float bv = bias[c];
  ushort_t* yo = y + plane;
  yo[(hh0    ) * 32 + ww] = f2b(a0 + bv);
  yo[(hh0 + 1) * 32 + ww] = f2b(a1 + bv);
  yo[(hh0 + 2) * 32 + ww] = f2b(a2 + bv);
  yo[(hh0 + 3) * 32 + ww] = f2b(a3 + bv);
}

// LayerNorm over C=384 + NCHW->NHWC transpose. Block per (b,h); out NHWC bf16.
__global__ __launch_bounds__(256) void k_lnT(const ushort_t* __restrict__ y,
                                             const float* __restrict__ lw,
                                             const float* __restrict__ lb,
                                             ushort_t* __restrict__ t) {
  __shared__ ushort_t tl[32 * 392];
  __shared__ float rsum[8][32], rsq[8][32];
  __shared__ float smu[32], srs[32];
  int bh = blockIdx.x;
  int b = bh >> 5, h = bh & 31;
  int tid = threadIdx.x;
  int w = tid & 31, cg = tid >> 5;
  const ushort_t* base = y + ((size_t)b * 384) * 1024 + h * 32 + w;
  float v[48];
  float s1 = 0.f, s2 = 0.f;
#pragma unroll
  for (int k = 0; k < 48; ++k) {
    int c = cg * 48 + k;
    float f = b2f(base[(size_t)c * 1024]);
    v[k] = f; s1 += f; s2 += f * f;
  }
  rsum[cg][w] = s1; rsq[cg][w] = s2;
  __syncthreads();
  if (tid < 32) {
    float a = 0.f, q = 0.f;
#pragma unroll
    for (int g = 0; g < 8; ++g) { a += rsum[g][tid]; q += rsq[g][tid]; }
    float mu = a * (1.f / 384.f);
    float var = q * (1.f / 384.f) - mu * mu;
    smu[tid] = mu; srs[tid] = rsqrtf(var + 1e-6f);
  }
  __syncthreads();
  float mu = smu[w], rs = srs[w];
#pragma unroll
  for (int k = 0; k < 48; ++k) {
    int c = cg * 48 + k;
    tl[w * 392 + c] = f2b((v[k] - mu) * rs * lw[c] + lb[c]);
  }
  __syncthreads();
  ushort_t* orow = t + (size_t)bh * 32 * 384;
#pragma unroll
  for (int i = 0; i < 6; ++i) {
    int flat16 = i * 256 + tid;
    int ww = flat16 / 48, c8 = flat16 % 48;
    *(uint4*)(orow + ww * 384 + c8 * 8) = *(const uint4*)(tl + ww * 392 + c8 * 8);
  }
}

__device__ __forceinline__ void gl_lds16(const void* g, void* l) {
  __builtin_amdgcn_global_load_lds(
      (const __attribute__((address_space(1))) unsigned int*)g,
      (__attribute__((address_space(3))) unsigned int*)l, 16, 0, 0);
}

#define MFMA_BF16 __builtin_amdgcn_mfma_f32_16x16x32_bf16

// ---------------- GEMM1 ----------------
// hid[m,n] = gelu(A[M,384] @ W1[1536,384]^T + bias); tile 256m x 128n, 8 waves,
// BK=32, 3-buffer LDS, counted vmcnt(3), XOR swizzle, transposed acc.
// Step body phase-split into 4 MFMA quadrants interleaved with grouped ds_reads
// (sched_barrier-pinned) + setprio around MFMA clusters: ds_read of the next
// quadrant's fragments overlaps MFMA of the current one; waves drift per-wave
// via counted lgkmcnt (compiler-inserted) instead of bursting in lockstep.
template <int T>
__device__ __forceinline__ void g1_body(const ushort_t* __restrict__ Ag0,
                                        const ushort_t* __restrict__ Ag1,
                                        const ushort_t* __restrict__ Bg,
                                        ushort_t (*As)[8192], ushort_t (*Bs)[4096],
                                        int wo, int wm, int wn, int l16, int quadA,
                                        f32x4 (&acc)[4][4]) {
  if (T < 11) asm volatile("s_waitcnt vmcnt(3)" ::: "memory");
  else        asm volatile("s_waitcnt vmcnt(0)" ::: "memory");
  __builtin_amdgcn_s_barrier();
  __builtin_amdgcn_sched_barrier(0);
  if (T + 2 < 12) {
    const int k2 = (T + 2) * 32;
    const int b2 = (T + 2) % 3;
    gl_lds16(Ag0 + k2, As[b2] + wo);
    gl_lds16(Ag1 + k2, As[b2] + 4096 + wo);
    gl_lds16(Bg + k2,  Bs[b2] + wo);
  }
  __builtin_amdgcn_sched_barrier(0);
  const ushort_t* Asc = As[T % 3];
  const ushort_t* Bsc = Bs[T % 3];
  // group 1: fragments for quadrant 0
  bf16x8 af0 = *(const bf16x8*)(Asc + (wm      + l16) * 32 + quadA * 8);
  bf16x8 af1 = *(const bf16x8*)(Asc + (wm + 16 + l16) * 32 + quadA * 8);
  bf16x8 bf0 = *(const bf16x8*)(Bsc + (wn      + l16) * 32 + quadA * 8);
  bf16x8 bf1 = *(const bf16x8*)(Bsc + (wn + 16 + l16) * 32 + quadA * 8);
  __builtin_amdgcn_sched_barrier(0);
  // group 2 issued while Q0 executes
  bf16x8 af2 = *(const bf16x8*)(Asc + (wm + 32 + l16) * 32 + quadA * 8);
  bf16x8 af3 = *(const bf16x8*)(Asc + (wm + 48 + l16) * 32 + quadA * 8);
  __builtin_amdgcn_sched_barrier(0);
  __builtin_amdgcn_s_setprio(1);
  acc[0][0] = MFMA_BF16(bf0, af0, acc[0][0], 0, 0, 0);
  acc[0][1] = MFMA_BF16(bf1, af0, acc[0][1], 0, 0, 0);
  acc[1][0] = MFMA_BF16(bf0, af1, acc[1][0], 0, 0, 0);
  acc[1][1] = MFMA_BF16(bf1, af1, acc[1][1], 0, 0, 0);
  __builtin_amdgcn_s_setprio(0);
  __builtin_amdgcn_sched_barrier(0);
  // group 3 issued while Q1 executes
  bf16x8 bf2 = *(const bf16x8*)(Bsc + (wn + 32 + l16) * 32 + quadA * 8);
  bf16x8 bf3 = *(const bf16x8*)(Bsc + (wn + 48 + l16) * 32 + quadA * 8);
  __builtin_amdgcn_sched_barrier(0);
  __builtin_amdgcn_s_setprio(1);
  acc[2][0] = MFMA_BF16(bf0, af2, acc[2][0], 0, 0, 0);
  acc[2][1] = MFMA_BF16(bf1, af2, acc[2][1], 0, 0, 0);
  acc[3][0] = MFMA_BF16(bf0, af3, acc[3][0], 0, 0, 0);
  acc[3][1] = MFMA_BF16(bf1, af3, acc[3][1], 0, 0, 0);
  __builtin_amdgcn_sched_barrier(0);
  acc[2][2] = MFMA_BF16(bf2, af2, acc[2][2], 0, 0, 0);
  acc[2][3] = MFMA_BF16(bf3, af2, acc[2][3], 0, 0, 0);
  acc[3][2] = MFMA_BF16(bf2, af3, acc[3][2], 0, 0, 0);
  acc[3][3] = MFMA_BF16(bf3, af3, acc[3][3], 0, 0, 0);
  acc[0][2] = MFMA_BF16(bf2, af0, acc[0][2], 0, 0, 0);
  acc[0][3] = MFMA_BF16(bf3, af0, acc[0][3], 0, 0, 0);
  acc[1][2] = MFMA_BF16(bf2, af1, acc[1][2], 0, 0, 0);
  acc[1][3] = MFMA_BF16(bf3, af1, acc[1][3], 0, 0, 0);
  __builtin_amdgcn_s_setprio(0);
}

__global__ __launch_bounds__(512, 4) void k_gemm1(const ushort_t* __restrict__ A,
                                                  const ushort_t* __restrict__ Bt,
                                                  const float* __restrict__ bias,
                                                  ushort_t* __restrict__ out) {
  const int N = 1536;
  const int K = 384;
  __shared__ ushort_t As[3][8192];
  __shared__ ushort_t Bs[3][4096];
  const int tid = threadIdx.x;
  const int wid = tid >> 6;
  const int lane = tid & 63;
  const int quad = lane >> 4;
  const int l16 = lane & 15;
  int lin = blockIdx.y * 12 + blockIdx.x;
  const int cpx = (12 * (int)gridDim.y) >> 3;  // nwg/8, nwg%8==0
  lin = (lin & 7) * cpx + (lin >> 3);
  const int m0 = (lin / 12) * 256;
  const int n0 = (lin % 12) * 128;
  const int wm = (wid & 3) * 64;
  const int wn = (wid >> 2) * 64;
  const int row = tid >> 2;                    // 0..127
  const int seg = (tid & 3) ^ ((tid >> 3) & 3);
  const int quadA = quad ^ ((l16 >> 1) & 3);
  const ushort_t* Ag0 = A + (size_t)(m0 + row) * K + seg * 8;   // rows 0..127
  const ushort_t* Ag1 = Ag0 + (size_t)128 * K;                  // rows 128..255
  const ushort_t* Bg  = Bt + (size_t)(n0 + row) * K + seg * 8;  // 128 rows
  const int wo = wid * 512;
  f32x4 acc[4][4] = {};
  // prologue: tiles 0,1 (6 calls in flight)
  gl_lds16(Ag0, As[0] + wo);
  gl_lds16(Ag1, As[0] + 4096 + wo);
  gl_lds16(Bg,  Bs[0] + wo);
  gl_lds16(Ag0 + 32, As[1] + wo);
  gl_lds16(Ag1 + 32, As[1] + 4096 + wo);
  gl_lds16(Bg + 32,  Bs[1] + wo);
  g1_body<0>(Ag0, Ag1, Bg, As, Bs, wo, wm, wn, l16, quadA, acc);
  g1_body<1>(Ag0, Ag1, Bg, As, Bs, wo, wm, wn, l16, quadA, acc);
  g1_body<2>(Ag0, Ag1, Bg, As, Bs, wo, wm, wn, l16, quadA, acc);
  g1_body<3>(Ag0, Ag1, Bg, As, Bs, wo, wm, wn, l16, quadA, acc);
  g1_body<4>(Ag0, Ag1, Bg, As, Bs, wo, wm, wn, l16, quadA, acc);
  g1_body<5>(Ag0, Ag1, Bg, As, Bs, wo, wm, wn, l16, quadA, acc);
  g1_body<6>(Ag0, Ag1, Bg, As, Bs, wo, wm, wn, l16, quadA, acc);
  g1_body<7>(Ag0, Ag1, Bg, As, Bs, wo, wm, wn, l16, quadA, acc);
  g1_body<8>(Ag0, Ag1, Bg, As, Bs, wo, wm, wn, l16, quadA, acc);
  g1_body<9>(Ag0, Ag1, Bg, As, Bs, wo, wm, wn, l16, quadA, acc);
  g1_body<10>(Ag0, Ag1, Bg, As, Bs, wo, wm, wn, l16, quadA, acc);
  g1_body<11>(Ag0, Ag1, Bg, As, Bs, wo, wm, wn, l16, quadA, acc);
  // epilogue: lane holds m = m0+wm+i*16+l16, n = n0+wn+j*16+quad*4+r
  const size_t mrow = (size_t)(m0 + wm + l16) * N;
#pragma unroll
  for (int j = 0; j < 4; ++j) {
    const int nbg = n0 + wn + j * 16 + quad * 4;
    const float4 bv = *(const float4*)(bias + nbg);
#pragma unroll
    for (int i = 0; i < 4; ++i) {
      float v0 = fgelu(acc[i][j][0] + bv.x);
      float v1 = fgelu(acc[i][j][1] + bv.y);
      float v2 = fgelu(acc[i][j][2] + bv.z);
      float v3 = fgelu(acc[i][j][3] + bv.w);
      unsigned lo, hi;
      asm("v_cvt_pk_bf16_f32 %0, %1, %2" : "=v"(lo) : "v"(v0), "v"(v1));
      asm("v_cvt_pk_bf16_f32 %0, %1, %2" : "=v"(hi) : "v"(v2), "v"(v3));
      *(uint2*)(out + mrow + (size_t)(i * 16) * N + nbg) = make_uint2(lo, hi);
    }
  }
}

// ---------------- GEMM2 + fused residual ----------------
// out[b,c,sp] = x + (A@Bt^T + b2)*gamma, NCHW; tile 256m x 128n, 8 waves,
// same 3-buffer counted-vmcnt pipeline with the 4-quadrant phase-split body;
// 2-phase 64x260f transpose epilogue aliased over the 72KB staging LDS.
__global__ __launch_bounds__(512, 4) void k_gemm2(const ushort_t* __restrict__ A,
                                                  const ushort_t* __restrict__ Bt,
                                                  const float* __restrict__ bias,
                                                  const float* __restrict__ scale,
                                                  const float* __restrict__ x,
                                                  float* __restrict__ out,
                                                  int mbase) {
  const int K = 1536;
  const int nt = 48;
  __shared__ __align__(16) char smem[73728];
  ushort_t* AsB = (ushort_t*)smem;        // 3 x 8192 ushorts
  ushort_t* BsB = AsB + 24576;            // 3 x 4096 ushorts
  float* tb = (float*)smem;               // epilogue 64x260 floats (aliased)
  const int tid = threadIdx.x;
  const int wid = tid >> 6;
  const int lane = tid & 63;
  const int quad = lane >> 4;
  const int l16 = lane & 15;
  int lin = blockIdx.y * 3 + blockIdx.x;
  const int cpx = (3 * (int)gridDim.y) >> 3;
  lin = (lin & 7) * cpx + (lin >> 3);
  const int m0 = (lin / 3) * 256;
  const int n0 = (lin % 3) * 128;
  const int wm = (wid & 3) * 64;
  const int wn = (wid >> 2) * 64;
  const int row = tid >> 2;
  const int seg = (tid & 3) ^ ((tid >> 3) & 3);
  const int quadA = quad ^ ((l16 >> 1) & 3);
  const ushort_t* Ag0 = A + (size_t)(m0 + row) * K + seg * 8;
  const ushort_t* Ag1 = Ag0 + (size_t)128 * K;
  const ushort_t* Bg  = Bt + (size_t)(n0 + row) * K + seg * 8;
  const int wo = wid * 512;
  f32x4 acc[4][4] = {};
  // prologue
  gl_lds16(Ag0, AsB + wo);
  gl_lds16(Ag1, AsB + 4096 + wo);
  gl_lds16(Bg,  BsB + wo);
  gl_lds16(Ag0 + 32, AsB + 8192 + wo);
  gl_lds16(Ag1 + 32, AsB + 8192 + 4096 + wo);
  gl_lds16(Bg + 32,  BsB + 4096 + wo);
  int rb = 0, wb = 2;
  for (int t = 0; t < nt; ++t) {
    if (t < nt - 1) asm volatile("s_waitcnt vmcnt(3)" ::: "memory");
    else            asm volatile("s_waitcnt vmcnt(0)" ::: "memory");
    __builtin_amdgcn_s_barrier();
    __builtin_amdgcn_sched_barrier(0);
    if (t < nt - 2) {
      const int k2 = (t + 2) << 5;
      ushort_t* Asn = AsB + wb * 8192;
      ushort_t* Bsn = BsB + wb * 4096;
      gl_lds16(Ag0 + k2, Asn + wo);
      gl_lds16(Ag1 + k2, Asn + 4096 + wo);
      gl_lds16(Bg + k2,  Bsn + wo);
    }
    __builtin_amdgcn_sched_barrier(0);
    const ushort_t* Asc = AsB + rb * 8192;
    const ushort_t* Bsc = BsB + rb * 4096;
    bf16x8 af0 = *(const bf16x8*)(Asc + (wm      + l16) * 32 + quadA * 8);
    bf16x8 af1 = *(const bf16x8*)(Asc + (wm + 16 + l16) * 32 + quadA * 8);
    bf16x8 bf0 = *(const bf16x8*)(Bsc + (wn      + l16) * 32 + quadA * 8);
    bf16x8 bf1 = *(const bf16x8*)(Bsc + (wn + 16 + l16) * 32 + quadA * 8);
    __builtin_amdgcn_sched_barrier(0);
    bf16x8 af2 = *(const bf16x8*)(Asc + (wm + 32 + l16) * 32 + quadA * 8);
    bf16x8 af3 = *(const bf16x8*)(Asc + (wm + 48 + l16) * 32 + quadA * 8);
    __builtin_amdgcn_sched_barrier(0);
    __builtin_amdgcn_s_setprio(1);
    acc[0][0] = MFMA_BF16(af0, bf0, acc[0][0], 0, 0, 0);
    acc[0][1] = MFMA_BF16(af0, bf1, acc[0][1], 0, 0, 0);
    acc[1][0] = MFMA_BF16(af1, bf0, acc[1][0], 0, 0, 0);
    acc[1][1] = MFMA_BF16(af1, bf1, acc[1][1], 0, 0, 0);
    __builtin_amdgcn_s_setprio(0);
    __builtin_amdgcn_sched_barrier(0);
    bf16x8 bf2 = *(const bf16x8*)(Bsc + (wn + 32 + l16) * 32 + quadA * 8);
    bf16x8 bf3 = *(const bf16x8*)(Bsc + (wn + 48 + l16) * 32 + quadA * 8);
    __builtin_amdgcn_sched_barrier(0);
    __builtin_amdgcn_s_setprio(1);
    acc[2][0] = MFMA_BF16(af2, bf0, acc[2][0], 0, 0, 0);
    acc[2][1] = MFMA_BF16(af2, bf1, acc[2][1], 0, 0, 0);
    acc[3][0] = MFMA_BF16(af3, bf0, acc[3][0], 0, 0, 0);
    acc[3][1] = MFMA_BF16(af3, bf1, acc[3][1], 0, 0, 0);
    __builtin_amdgcn_sched_barrier(0);
    acc[2][2] = MFMA_BF16(af2, bf2, acc[2][2], 0, 0, 0);
    acc[2][3] = MFMA_BF16(af2, bf3, acc[2][3], 0, 0, 0);
    acc[3][2] = MFMA_BF16(af3, bf2, acc[3][2], 0, 0, 0);
    acc[3][3] = MFMA_BF16(af3, bf3, acc[3][3], 0, 0, 0);
    acc[0][2] = MFMA_BF16(af0, bf2, acc[0][2], 0, 0, 0);
    acc[0][3] = MFMA_BF16(af0, bf3, acc[0][3], 0, 0, 0);
    acc[1][2] = MFMA_BF16(af1, bf2, acc[1][2], 0, 0, 0);
    acc[1][3] = MFMA_BF16(af1, bf3, acc[1][3], 0, 0, 0);
    __builtin_amdgcn_s_setprio(0);
    rb = (rb == 2) ? 0 : rb + 1;
    wb = (wb == 2) ? 0 : wb + 1;
  }
  const int mg = mbase + m0;
  const int b = mg >> 10;
  const int sp0 = mg & 1023;
#pragma unroll
  for (int p = 0; p < 2; ++p) {
    __syncthreads();
    if ((wid >> 2) == p) {   // 4 m-waves of this n-half write acc -> tb
#pragma unroll
      for (int j = 0; j < 4; ++j) {
        int nl = j * 16 + l16;
        int cch = n0 + p * 64 + nl;
        float bv = bias[cch], sv = scale[cch];
#pragma unroll
        for (int i = 0; i < 4; ++i) {
          int ml = wm + i * 16 + quad * 4;
          *(float4*)(tb + nl * 260 + ml) = make_float4(
              (acc[i][j][0] + bv) * sv, (acc[i][j][1] + bv) * sv,
              (acc[i][j][2] + bv) * sv, (acc[i][j][3] + bv) * sv);
        }
      }
    }
    __syncthreads();
#pragma unroll
    for (int q = 0; q < 8; ++q) {
      int flat4 = q * 512 + tid;          // [0,4096): 64 chans x 64 float4
      int cl = flat4 >> 6;
      int m4 = (flat4 & 63) << 2;
      size_t ga = (((size_t)b * 384 + n0 + p * 64 + cl) << 10) + sp0 + m4;
      float4 xv = *(const float4*)(x + ga);
      float4 tv = *(const float4*)(tb + cl * 260 + m4);
      *(float4*)(out + ga) = make_float4(xv.x + tv.x, xv.y + tv.y,
                                         xv.z + tv.z, xv.w + tv.w);
    }
  }
}

extern "C" void kernel_launch(void* const* d_in, const int* in_sizes, int n_in,
                              void* d_out, int out_size, void* d_ws, size_t ws_size,
                              hipStream_t stream) {
  const float* x        = (const float*)d_in[0];
  const float* kp_w1    = (const float*)d_in[1];
  const float* bn_gamma = (const float*)d_in[2];
  const float* bn_beta  = (const float*)d_in[3];
  const float* bn_mean  = (const float*)d_in[4];
  const float* bn_var   = (const float*)d_in[5];
  const float* kp_w2    = (const float*)d_in[6];
  const float* kp_b2    = (const float*)d_in[7];
  const float* fn_std   = (const float*)d_in[8];
  const float* fn_mean  = (const float*)d_in[9];
  const float* bias     = (const float*)d_in[10];
  const float* ln_w     = (const float*)d_in[11];
  const float* ln_b     = (const float*)d_in[12];
  const float* w1       = (const float*)d_in[13];
  const float* b1       = (const float*)d_in[14];
  const float* w2       = (const float*)d_in[15];
  const float* b2       = (const float*)d_in[16];
  const float* gamma    = (const float*)d_in[17];
  float* out = (float*)d_out;

  char* ws = (char*)d_ws;
  float*    praw   = (float*)(ws + 0);            // 6291456
  float*    pB     = (float*)(ws + 6291456);      // 98304
  float*    hbuf   = (float*)(ws + 6389760);      // 6144
  float2*   part   = (float2*)(ws + 6395904);     // 49152
  float2*   stats  = (float2*)(ws + 6445056);     // 512
  ushort_t* w1b    = (ushort_t*)(ws + 6445568);   // 1179648
  ushort_t* w2b    = (ushort_t*)(ws + 7625216);   // 1179648
  ushort_t* ybuf   = (ushort_t*)(ws + 8804864);   // 50331648
  ushort_t* tn     = (ushort_t*)(ws + 59136512);  // 50331648
  ushort_t* hid    = (ushort_t*)(ws + 109468160); // up to 201326592

  // chunking: hid for M-rows/chunk of the 65536-row MLP
  int nchunks;
  if (ws_size >= 310794752ULL) nchunks = 1;
  else if (ws_size >= 210131456ULL) nchunks = 2;
  else nchunks = 4;
  int mrows = 65536 / nchunks;

  k_tobf16<<<2304, 256, 0, stream>>>(w1, w1b, 589824);
  k_tobf16<<<2304, 256, 0, stream>>>(w2, w2b, 589824);
  k_pool<<<6144, 256, 0, stream>>>(x, pB);
  k_h<<<dim3(24, 64), 64, 0, stream>>>(pB, kp_w1, bn_gamma, bn_beta, bn_mean,
                                       bn_var, hbuf);
  k_praw<<<dim3(96, 64), 256, 0, stream>>>(hbuf, kp_w2, kp_b2, praw, part);
  k_pstat<<<64, 128, 0, stream>>>(part, stats);
  k_conv<<<dim3(384, 64), 256, 0, stream>>>(x, praw, stats, fn_std, fn_mean,
                                            bias, ybuf);
  k_lnT<<<2048, 256, 0, stream>>>(ybuf, ln_w, ln_b, tn);
  for (int s = 0; s < nchunks; ++s) {
    k_gemm1<<<dim3(12, mrows / 256), 512, 0, stream>>>(
        tn + (size_t)s * mrows * 384, w1b, b1, hid);
    k_gemm2<<<dim3(3, mrows / 256), 512, 0, stream>>>(
        hid, w2b, b2, gamma, x, out, s * mrows);
  }
}

// Round 7
// 378.989 us; speedup vs baseline: 1.1853x; 1.0346x over previous
//
#include <hip/hip_runtime.h>
#include <cstdint>

typedef unsigned short ushort_t;
typedef __bf16 bf16x8 __attribute__((ext_vector_type(8)));
typedef float f32x4 __attribute__((ext_vector_type(4)));

__device__ __forceinline__ ushort_t f2b(float f) {
  union { float f; unsigned u; } v; v.f = f;
  unsigned u = v.u;
  return (ushort_t)((u + 0x7FFFu + ((u >> 16) & 1u)) >> 16);
}
__device__ __forceinline__ float b2f(ushort_t h) {
  union { unsigned u; float f; } v; v.u = ((unsigned)h) << 16;
  return v.f;
}

// fast sigmoid-gelu: v * rcp(1 + exp(-1.702 v)); error suppressed by gamma=1e-6
__device__ __forceinline__ float fgelu(float v) {
  float e = __expf(v * -1.702f);
  return v * __builtin_amdgcn_rcpf(1.0f + e);
}

// f32 -> bf16 cast for weights
__global__ __launch_bounds__(256) void k_tobf16(const float* __restrict__ s,
                                                ushort_t* __restrict__ d, int n) {
  int i = blockIdx.x * 256 + threadIdx.x;
  if (i < n) d[i] = f2b(s[i]);
}

// p[b,c] = mean over 32x32 spatial; one wave per (b,c)
__global__ __launch_bounds__(256) void k_pool(const float* __restrict__ x,
                                              float* __restrict__ p) {
  int wid = threadIdx.x >> 6, lane = threadIdx.x & 63;
  int bc = blockIdx.x * 4 + wid;
  const float4* xr = (const float4*)(x + (size_t)bc * 1024);
  float s = 0.f;
#pragma unroll
  for (int i = 0; i < 4; ++i) {
    float4 t = xr[i * 64 + lane];
    s += (t.x + t.y) + (t.z + t.w);
  }
#pragma unroll
  for (int off = 32; off > 0; off >>= 1) s += __shfl_down(s, off);
  if (lane == 0) p[bc] = s * (1.0f / 1024.0f);
}

// h[b][o] = relu(bn(p[b] . kp_w1[o])); one wave per (o,b); grid (24,64), block 64
__global__ __launch_bounds__(64) void k_h(
    const float* __restrict__ p, const float* __restrict__ kp_w1,
    const float* __restrict__ bn_gamma, const float* __restrict__ bn_beta,
    const float* __restrict__ bn_mean, const float* __restrict__ bn_var,
    float* __restrict__ hbuf) {
  int o = blockIdx.x, b = blockIdx.y, lane = threadIdx.x;
  const float* pr = p + b * 384;
  const float* wr = kp_w1 + o * 384;
  float s = 0.f;
#pragma unroll
  for (int i = 0; i < 6; ++i) {
    int c = i * 64 + lane;
    s += pr[c] * wr[c];
  }
#pragma unroll
  for (int off = 32; off > 0; off >>= 1) s += __shfl_down(s, off);
  if (lane == 0) {
    float a = (s - bn_mean[o]) * rsqrtf(bn_var[o] + 1e-5f) * bn_gamma[o] + bn_beta[o];
    hbuf[b * 24 + o] = fmaxf(a, 0.f);
  }
}

// praw[b][j] = h[b].kp_w2[j] + kp_b2[j]; per-block partial sums -> part[b][bx]
// grid (96, 64), block 256
__global__ __launch_bounds__(256) void k_praw(
    const float* __restrict__ hbuf, const float* __restrict__ kp_w2,
    const float* __restrict__ kp_b2, float* __restrict__ praw,
    float2* __restrict__ part) {
  __shared__ float wrow[256 * 25];
  __shared__ float hs[24];
  __shared__ float r1[256], r2[256];
  int bx = blockIdx.x, b = blockIdx.y, tid = threadIdx.x;
  int j0 = bx * 256;
  for (int t = tid; t < 6144; t += 256) {
    int row = t / 24, col = t - row * 24;
    wrow[row * 25 + col] = kp_w2[(size_t)j0 * 24 + t];
  }
  if (tid < 24) hs[tid] = hbuf[b * 24 + tid];
  __syncthreads();
  float a = kp_b2[j0 + tid];
  const float* wr = wrow + tid * 25;
#pragma unroll
  for (int r = 0; r < 24; ++r) a += hs[r] * wr[r];
  praw[(size_t)b * 24576 + j0 + tid] = a;
  r1[tid] = a; r2[tid] = a * a;
  __syncthreads();
  for (int off = 128; off > 0; off >>= 1) {
    if (tid < off) { r1[tid] += r1[tid + off]; r2[tid] += r2[tid + off]; }
    __syncthreads();
  }
  if (tid == 0) part[b * 96 + bx] = make_float2(r1[0], r2[0]);
}

// stats[b] = (u, rsqrt(var)); grid 64, block 128 (96 active)
__global__ __launch_bounds__(128) void k_pstat(const float2* __restrict__ part,
                                               float2* __restrict__ stats) {
  __shared__ float r1[128], r2[128];
  int b = blockIdx.x, tid = threadIdx.x;
  float2 v = (tid < 96) ? part[b * 96 + tid] : make_float2(0.f, 0.f);
  r1[tid] = v.x; r2[tid] = v.y;
  __syncthreads();
  for (int off = 64; off > 0; off >>= 1) {
    if (tid < off) { r1[tid] += r1[tid + off]; r2[tid] += r2[tid + off]; }
    __syncthreads();
  }
  if (tid == 0) {
    float u = r1[0] * (1.f / 24576.f);
    float var = r2[0] * (1.f / 24576.f) - u * u;
    stats[b] = make_float2(u, rsqrtf(var + 1e-12f));
  }
}

// circulant conv per (b,c); writes y NCHW bf16 = conv + bias.
// Frame-norm affine applied on param load. grid (384, 64)
__global__ __launch_bounds__(256) void k_conv(const float* __restrict__ x,
                                              const float* __restrict__ praw,
                                              const float2* __restrict__ stats,
                                              const float* __restrict__ fn_std,
                                              const float* __restrict__ fn_mean,
                                              const float* __restrict__ bias,
                                              ushort_t* __restrict__ y) {
  __shared__ float xs[1024];
  __shared__ float pe[32];
  __shared__ float kn[32];
  int c = blockIdx.x, b = blockIdx.y;
  int tid = threadIdx.x;
  size_t plane = ((size_t)b * 384 + c) * 1024;
  float4 xv = ((const float4*)(x + plane))[tid];
  if (tid < 32) {
    float2 st = stats[b];
    int j1 = c * 32 + tid;
    int j2 = (384 + c) * 32 + tid;
    pe[tid] = (praw[(size_t)b * 24576 + j1] - st.x) * st.y * fn_std[j1] + fn_mean[j1];
    kn[tid] = (praw[(size_t)b * 24576 + j2] - st.x) * st.y * fn_std[j2] + fn_mean[j2];
  }
  __syncthreads();
  const bool hm = (c < 192);
  {
    int e0 = tid * 4;
    float4 t;
    if (hm) {
      float pv = pe[e0 >> 5];
      t.x = xv.x + pv; t.y = xv.y + pv; t.z = xv.z + pv; t.w = xv.w + pv;
    } else {
      int w0 = e0 & 31;
      t.x = xv.x + pe[w0]; t.y = xv.y + pe[w0 + 1];
      t.z = xv.z + pe[w0 + 2]; t.w = xv.w + pe[w0 + 3];
    }
    *(float4*)(xs + e0) = t;
  }
  __syncthreads();
  int ww = tid & 31, hh0 = (tid >> 5) * 4;
  float a0 = 0, a1 = 0, a2 = 0, a3 = 0;
  if (hm) {
    float c0 = xs[hh0 * 32 + ww], c1 = xs[(hh0 + 1) * 32 + ww];
    float c2 = xs[(hh0 + 2) * 32 + ww], c3 = xs[(hh0 + 3) * 32 + ww];
#pragma unroll
    for (int d = 0; d < 32; ++d) {
      float kv = kn[d];
      a0 += kv * c0; a1 += kv * c1; a2 += kv * c2; a3 += kv * c3;
      c0 = c1; c1 = c2; c2 = c3;
      c3 = xs[(((hh0 + d + 4) & 31) << 5) + ww];
    }
  } else {
#pragma unroll
    for (int d = 0; d < 32; ++d) {
      float kv = kn[d];
      int wc = (ww + d) & 31;
      a0 += kv * xs[(hh0    ) * 32 + wc];
      a1 += kv * xs[(hh0 + 1) * 32 + wc];
      a2 += kv * xs[(hh0 + 2) * 32 + wc];
      a3 += kv * xs[(hh0 + 3) * 32 + wc];
    }
  }
  float bv = bias[c];
  ushort_t* yo = y + plane;
  yo[(hh0    ) * 32 + ww] = f2b(a0 + bv);
  yo[(hh0 + 1) * 32 + ww] = f2b(a1 + bv);
  yo[(hh0 + 2) * 32 + ww] = f2b(a2 + bv);
  yo[(hh0 + 3) * 32 + ww] = f2b(a3 + bv);
}

// LayerNorm over C=384 + NCHW->NHWC transpose. Block per (b,h); out NHWC bf16.
__global__ __launch_bounds__(256) void k_lnT(const ushort_t* __restrict__ y,
                                             const float* __restrict__ lw,
                                             const float* __restrict__ lb,
                                             ushort_t* __restrict__ t) {
  __shared__ ushort_t tl[32 * 392];
  __shared__ float rsum[8][32], rsq[8][32];
  __shared__ float smu[32], srs[32];
  int bh = blockIdx.x;
  int b = bh >> 5, h = bh & 31;
  int tid = threadIdx.x;
  int w = tid & 31, cg = tid >> 5;
  const ushort_t* base = y + ((size_t)b * 384) * 1024 + h * 32 + w;
  float v[48];
  float s1 = 0.f, s2 = 0.f;
#pragma unroll
  for (int k = 0; k < 48; ++k) {
    int c = cg * 48 + k;
    float f = b2f(base[(size_t)c * 1024]);
    v[k] = f; s1 += f; s2 += f * f;
  }
  rsum[cg][w] = s1; rsq[cg][w] = s2;
  __syncthreads();
  if (tid < 32) {
    float a = 0.f, q = 0.f;
#pragma unroll
    for (int g = 0; g < 8; ++g) { a += rsum[g][tid]; q += rsq[g][tid]; }
    float mu = a * (1.f / 384.f);
    float var = q * (1.f / 384.f) - mu * mu;
    smu[tid] = mu; srs[tid] = rsqrtf(var + 1e-6f);
  }
  __syncthreads();
  float mu = smu[w], rs = srs[w];
#pragma unroll
  for (int k = 0; k < 48; ++k) {
    int c = cg * 48 + k;
    tl[w * 392 + c] = f2b((v[k] - mu) * rs * lw[c] + lb[c]);
  }
  __syncthreads();
  ushort_t* orow = t + (size_t)bh * 32 * 384;
#pragma unroll
  for (int i = 0; i < 6; ++i) {
    int flat16 = i * 256 + tid;
    int ww = flat16 / 48, c8 = flat16 % 48;
    *(uint4*)(orow + ww * 384 + c8 * 8) = *(const uint4*)(tl + ww * 392 + c8 * 8);
  }
}

__device__ __forceinline__ void gl_lds16(const void* g, void* l) {
  __builtin_amdgcn_global_load_lds(
      (const __attribute__((address_space(1))) unsigned int*)g,
      (__attribute__((address_space(3))) unsigned int*)l, 16, 0, 0);
}

#define MFMA_BF16 __builtin_amdgcn_mfma_f32_16x16x32_bf16
#define SBAR  __builtin_amdgcn_s_barrier
#define SCHB  __builtin_amdgcn_sched_barrier
#define LGKM0 asm volatile("s_waitcnt lgkmcnt(0)" ::: "memory")

// ---------------- GEMM1 (barrier-clocked 2-phase pipeline) ----------------
// hid[m,n] = gelu(A[M,384] @ W1[1536,384]^T + bias); tile 256m x 128n.
// 4 waves, wave-tile 128m x 64n (32 MFMA/step in 2 clusters of 16 = m201
// cluster size). BK=32, 3-buffer LDS (72KB), counted vmcnt(6), 4 barriers/step:
//   P0: ds_read af0-7+bf01 | stage A(t+2)x4 | bar | lgkm0 | 16 MFMA j01 | bar
//   P1: ds_read bf23       | stage B(t+2)x2 | bar | lgkm0 | 16 MFMA j23
// XOR swizzle + transposed acc (mfma(b,a)) identical to verified r5 layout.
__global__ __launch_bounds__(256, 2) void k_gemm1(const ushort_t* __restrict__ A,
                                                  const ushort_t* __restrict__ Bt,
                                                  const float* __restrict__ bias,
                                                  ushort_t* __restrict__ out) {
  const int N = 1536;
  const int K = 384;
  const int nt = 12;
  __shared__ ushort_t As[3][8192];
  __shared__ ushort_t Bs[3][4096];
  const int tid = threadIdx.x;
  const int wid = tid >> 6;
  const int lane = tid & 63;
  const int quad = lane >> 4;
  const int l16 = lane & 15;
  int lin = blockIdx.y * 12 + blockIdx.x;
  const int cpx = (12 * (int)gridDim.y) >> 3;  // nwg/8, nwg%8==0
  lin = (lin & 7) * cpx + (lin >> 3);
  const int m0 = (lin / 12) * 256;
  const int n0 = (lin % 12) * 128;
  const int wm = (wid & 1) * 128;
  const int wn = (wid >> 1) * 64;
  const int row = tid >> 2;                    // 0..63
  const int seg = (tid & 3) ^ ((tid >> 3) & 3);
  const int quadA = quad ^ ((l16 >> 1) & 3);
  const ushort_t* Ag = A + (size_t)(m0 + row) * K + seg * 8;
  const ushort_t* Bg = Bt + (size_t)(n0 + row) * K + seg * 8;
  const int wo = wid * 512;                    // ushorts (1KB per wave)
  f32x4 acc[8][4] = {};
#define G1_STAGE_A(buf, k)                                        \
  gl_lds16(Ag + (k), As[buf] + wo);                               \
  gl_lds16(Ag + (size_t)64 * K + (k), As[buf] + 2048 + wo);       \
  gl_lds16(Ag + (size_t)128 * K + (k), As[buf] + 4096 + wo);      \
  gl_lds16(Ag + (size_t)192 * K + (k), As[buf] + 6144 + wo);
#define G1_STAGE_B(buf, k)                                        \
  gl_lds16(Bg + (k), Bs[buf] + wo);                               \
  gl_lds16(Bg + (size_t)64 * K + (k), Bs[buf] + 2048 + wo);
  // prologue: tiles 0,1 (12 calls/wave in flight)
  G1_STAGE_A(0, 0) G1_STAGE_B(0, 0)
  G1_STAGE_A(1, 32) G1_STAGE_B(1, 32)
  int rb = 0, wb = 2;
  for (int t = 0; t < nt; ++t) {
    if (t < nt - 1) asm volatile("s_waitcnt vmcnt(6)" ::: "memory");
    else            asm volatile("s_waitcnt vmcnt(0)" ::: "memory");
    SBAR();                       // tile t visible block-wide
    SCHB(0);
    const ushort_t* Asc = As[rb];
    const ushort_t* Bsc = Bs[rb];
    bf16x8 af[8], bf0, bf1, bf2, bf3;
#pragma unroll
    for (int i = 0; i < 8; ++i)
      af[i] = *(const bf16x8*)(Asc + (wm + i * 16 + l16) * 32 + quadA * 8);
    bf0 = *(const bf16x8*)(Bsc + (wn      + l16) * 32 + quadA * 8);
    bf1 = *(const bf16x8*)(Bsc + (wn + 16 + l16) * 32 + quadA * 8);
    if (t + 2 < nt) { const int k2 = (t + 2) * 32; G1_STAGE_A(wb, k2) }
    SCHB(0);
    SBAR();                       // phase clock: all issued before compute
    LGKM0;
    SCHB(0);
    __builtin_amdgcn_s_setprio(1);
#pragma unroll
    for (int i = 0; i < 8; ++i) {
      acc[i][0] = MFMA_BF16(bf0, af[i], acc[i][0], 0, 0, 0);
      acc[i][1] = MFMA_BF16(bf1, af[i], acc[i][1], 0, 0, 0);
    }
    __builtin_amdgcn_s_setprio(0);
    SCHB(0);
    SBAR();                       // P1 entry
    SCHB(0);
    bf2 = *(const bf16x8*)(Bsc + (wn + 32 + l16) * 32 + quadA * 8);
    bf3 = *(const bf16x8*)(Bsc + (wn + 48 + l16) * 32 + quadA * 8);
    if (t + 2 < nt) { const int k2 = (t + 2) * 32; G1_STAGE_B(wb, k2) }
    SCHB(0);
    SBAR();
    LGKM0;
    SCHB(0);
    __builtin_amdgcn_s_setprio(1);
#pragma unroll
    for (int i = 0; i < 8; ++i) {
      acc[i][2] = MFMA_BF16(bf2, af[i], acc[i][2], 0, 0, 0);
      acc[i][3] = MFMA_BF16(bf3, af[i], acc[i][3], 0, 0, 0);
    }
    __builtin_amdgcn_s_setprio(0);
    rb = (rb == 2) ? 0 : rb + 1;
    wb = (wb == 2) ? 0 : wb + 1;
  }
  // epilogue: lane holds m = m0+wm+i*16+l16, n = n0+wn+j*16+quad*4+r
  const size_t mrow = (size_t)(m0 + wm + l16) * N;
#pragma unroll
  for (int j = 0; j < 4; ++j) {
    const int nbg = n0 + wn + j * 16 + quad * 4;
    const float4 bv = *(const float4*)(bias + nbg);
#pragma unroll
    for (int i = 0; i < 8; ++i) {
      float v0 = fgelu(acc[i][j][0] + bv.x);
      float v1 = fgelu(acc[i][j][1] + bv.y);
      float v2 = fgelu(acc[i][j][2] + bv.z);
      float v3 = fgelu(acc[i][j][3] + bv.w);
      unsigned lo, hi;
      asm("v_cvt_pk_bf16_f32 %0, %1, %2" : "=v"(lo) : "v"(v0), "v"(v1));
      asm("v_cvt_pk_bf16_f32 %0, %1, %2" : "=v"(hi) : "v"(v2), "v"(v3));
      *(uint2*)(out + mrow + (size_t)(i * 16) * N + nbg) = make_uint2(lo, hi);
    }
  }
#undef G1_STAGE_A
#undef G1_STAGE_B
}

// ---------------- GEMM2 + fused residual (same pipeline) ----------------
// out[b,c,sp] = x + (A@Bt^T + b2)*gamma, NCHW; tile 256m x 128n, 4 waves of
// 128m x 64n, nt=48, barrier-clocked 2-phase steps; 2-pass 64x260f transpose
// epilogue aliased over the 72KB staging LDS.
__global__ __launch_bounds__(256, 2) void k_gemm2(const ushort_t* __restrict__ A,
                                                  const ushort_t* __restrict__ Bt,
                                                  const float* __restrict__ bias,
                                                  const float* __restrict__ scale,
                                                  const float* __restrict__ x,
                                                  float* __restrict__ out,
                                                  int mbase) {
  const int K = 1536;
  const int nt = 48;
  __shared__ __align__(16) char smem[73728];
  ushort_t* AsB = (ushort_t*)smem;        // 3 x 8192 ushorts
  ushort_t* BsB = AsB + 24576;            // 3 x 4096 ushorts
  float* tb = (float*)smem;               // epilogue 64x260 floats (aliased)
  const int tid = threadIdx.x;
  const int wid = tid >> 6;
  const int lane = tid & 63;
  const int quad = lane >> 4;
  const int l16 = lane & 15;
  int lin = blockIdx.y * 3 + blockIdx.x;
  const int cpx = (3 * (int)gridDim.y) >> 3;
  lin = (lin & 7) * cpx + (lin >> 3);
  const int m0 = (lin / 3) * 256;
  const int n0 = (lin % 3) * 128;
  const int wm = (wid & 1) * 128;
  const int wn = (wid >> 1) * 64;
  const int row = tid >> 2;
  const int seg = (tid & 3) ^ ((tid >> 3) & 3);
  const int quadA = quad ^ ((l16 >> 1) & 3);
  const ushort_t* Ag = A + (size_t)(m0 + row) * K + seg * 8;
  const ushort_t* Bg = Bt + (size_t)(n0 + row) * K + seg * 8;
  const int wo = wid * 512;
  f32x4 acc[8][4] = {};
#define G2_STAGE_A(buf, k)                                              \
  gl_lds16(Ag + (k), AsB + (buf) * 8192 + wo);                          \
  gl_lds16(Ag + (size_t)64 * K + (k), AsB + (buf) * 8192 + 2048 + wo);  \
  gl_lds16(Ag + (size_t)128 * K + (k), AsB + (buf) * 8192 + 4096 + wo); \
  gl_lds16(Ag + (size_t)192 * K + (k), AsB + (buf) * 8192 + 6144 + wo);
#define G2_STAGE_B(buf, k)                                              \
  gl_lds16(Bg + (k), BsB + (buf) * 4096 + wo);                          \
  gl_lds16(Bg + (size_t)64 * K + (k), BsB + (buf) * 4096 + 2048 + wo);
  G2_STAGE_A(0, 0) G2_STAGE_B(0, 0)
  G2_STAGE_A(1, 32) G2_STAGE_B(1, 32)
  int rb = 0, wb = 2;
  for (int t = 0; t < nt; ++t) {
    if (t < nt - 1) asm volatile("s_waitcnt vmcnt(6)" ::: "memory");
    else            asm volatile("s_waitcnt vmcnt(0)" ::: "memory");
    SBAR();
    SCHB(0);
    const ushort_t* Asc = AsB + rb * 8192;
    const ushort_t* Bsc = BsB + rb * 4096;
    bf16x8 af[8], bf0, bf1, bf2, bf3;
#pragma unroll
    for (int i = 0; i < 8; ++i)
      af[i] = *(const bf16x8*)(Asc + (wm + i * 16 + l16) * 32 + quadA * 8);
    bf0 = *(const bf16x8*)(Bsc + (wn      + l16) * 32 + quadA * 8);
    bf1 = *(const bf16x8*)(Bsc + (wn + 16 + l16) * 32 + quadA * 8);
    if (t + 2 < nt) { const int k2 = (t + 2) * 32; G2_STAGE_A(wb, k2) }
    SCHB(0);
    SBAR();
    LGKM0;
    SCHB(0);
    __builtin_amdgcn_s_setprio(1);
#pragma unroll
    for (int i = 0; i < 8; ++i) {
      acc[i][0] = MFMA_BF16(af[i], bf0, acc[i][0], 0, 0, 0);
      acc[i][1] = MFMA_BF16(af[i], bf1, acc[i][1], 0, 0, 0);
    }
    __builtin_amdgcn_s_setprio(0);
    SCHB(0);
    SBAR();
    SCHB(0);
    bf2 = *(const bf16x8*)(Bsc + (wn + 32 + l16) * 32 + quadA * 8);
    bf3 = *(const bf16x8*)(Bsc + (wn + 48 + l16) * 32 + quadA * 8);
    if (t + 2 < nt) { const int k2 = (t + 2) * 32; G2_STAGE_B(wb, k2) }
    SCHB(0);
    SBAR();
    LGKM0;
    SCHB(0);
    __builtin_amdgcn_s_setprio(1);
#pragma unroll
    for (int i = 0; i < 8; ++i) {
      acc[i][2] = MFMA_BF16(af[i], bf2, acc[i][2], 0, 0, 0);
      acc[i][3] = MFMA_BF16(af[i], bf3, acc[i][3], 0, 0, 0);
    }
    __builtin_amdgcn_s_setprio(0);
    rb = (rb == 2) ? 0 : rb + 1;
    wb = (wb == 2) ? 0 : wb + 1;
  }
  const int mg = mbase + m0;
  const int b = mg >> 10;
  const int sp0 = mg & 1023;
#pragma unroll
  for (int p = 0; p < 2; ++p) {
    __syncthreads();
    if ((wid >> 1) == p) {   // 2 m-waves of this n-half write acc -> tb
#pragma unroll
      for (int j = 0; j < 4; ++j) {
        int nl = j * 16 + l16;
        int cch = n0 + p * 64 + nl;
        float bv = bias[cch], sv = scale[cch];
#pragma unroll
        for (int i = 0; i < 8; ++i) {
          int ml = wm + i * 16 + quad * 4;
          *(float4*)(tb + nl * 260 + ml) = make_float4(
              (acc[i][j][0] + bv) * sv, (acc[i][j][1] + bv) * sv,
              (acc[i][j][2] + bv) * sv, (acc[i][j][3] + bv) * sv);
        }
      }
    }
    __syncthreads();
#pragma unroll
    for (int q = 0; q < 16; ++q) {
      int flat4 = q * 256 + tid;          // [0,4096): 64 chans x 64 float4
      int cl = flat4 >> 6;
      int m4 = (flat4 & 63) << 2;
      size_t ga = (((size_t)b * 384 + n0 + p * 64 + cl) << 10) + sp0 + m4;
      float4 xv = *(const float4*)(x + ga);
      float4 tv = *(const float4*)(tb + cl * 260 + m4);
      *(float4*)(out + ga) = make_float4(xv.x + tv.x, xv.y + tv.y,
                                         xv.z + tv.z, xv.w + tv.w);
    }
  }
#undef G2_STAGE_A
#undef G2_STAGE_B
}

extern "C" void kernel_launch(void* const* d_in, const int* in_sizes, int n_in,
                              void* d_out, int out_size, void* d_ws, size_t ws_size,
                              hipStream_t stream) {
  const float* x        = (const float*)d_in[0];
  const float* kp_w1    = (const float*)d_in[1];
  const float* bn_gamma = (const float*)d_in[2];
  const float* bn_beta  = (const float*)d_in[3];
  const float* bn_mean  = (const float*)d_in[4];
  const float* bn_var   = (const float*)d_in[5];
  const float* kp_w2    = (const float*)d_in[6];
  const float* kp_b2    = (const float*)d_in[7];
  const float* fn_std   = (const float*)d_in[8];
  const float* fn_mean  = (const float*)d_in[9];
  const float* bias     = (const float*)d_in[10];
  const float* ln_w     = (const float*)d_in[11];
  const float* ln_b     = (const float*)d_in[12];
  const float* w1       = (const float*)d_in[13];
  const float* b1       = (const float*)d_in[14];
  const float* w2       = (const float*)d_in[15];
  const float* b2       = (const float*)d_in[16];
  const float* gamma    = (const float*)d_in[17];
  float* out = (float*)d_out;

  char* ws = (char*)d_ws;
  float*    praw   = (float*)(ws + 0);            // 6291456
  float*    pB     = (float*)(ws + 6291456);      // 98304
  float*    hbuf   = (float*)(ws + 6389760);      // 6144
  float2*   part   = (float2*)(ws + 6395904);     // 49152
  float2*   stats  = (float2*)(ws + 6445056);     // 512
  ushort_t* w1b    = (ushort_t*)(ws + 6445568);   // 1179648
  ushort_t* w2b    = (ushort_t*)(ws + 7625216);   // 1179648
  ushort_t* ybuf   = (ushort_t*)(ws + 8804864);   // 50331648
  ushort_t* tn     = (ushort_t*)(ws + 59136512);  // 50331648
  ushort_t* hid    = (ushort_t*)(ws + 109468160); // up to 201326592

  // chunking: hid for M-rows/chunk of the 65536-row MLP
  int nchunks;
  if (ws_size >= 310794752ULL) nchunks = 1;
  else if (ws_size >= 210131456ULL) nchunks = 2;
  else nchunks = 4;
  int mrows = 65536 / nchunks;

  k_tobf16<<<2304, 256, 0, stream>>>(w1, w1b, 589824);
  k_tobf16<<<2304, 256, 0, stream>>>(w2, w2b, 589824);
  k_pool<<<6144, 256, 0, stream>>>(x, pB);
  k_h<<<dim3(24, 64), 64, 0, stream>>>(pB, kp_w1, bn_gamma, bn_beta, bn_mean,
                                       bn_var, hbuf);
  k_praw<<<dim3(96, 64), 256, 0, stream>>>(hbuf, kp_w2, kp_b2, praw, part);
  k_pstat<<<64, 128, 0, stream>>>(part, stats);
  k_conv<<<dim3(384, 64), 256, 0, stream>>>(x, praw, stats, fn_std, fn_mean,
                                            bias, ybuf);
  k_lnT<<<2048, 256, 0, stream>>>(ybuf, ln_w, ln_b, tn);
  for (int s = 0; s < nchunks; ++s) {
    k_gemm1<<<dim3(12, mrows / 256), 256, 0, stream>>>(
        tn + (size_t)s * mrows * 384, w1b, b1, hid);
    k_gemm2<<<dim3(3, mrows / 256), 256, 0, stream>>>(
        hid, w2b, b2, gamma, x, out, s * mrows);
  }
}